// Round 8
// baseline (526.500 us; speedup 1.0000x reference)
//
#include <hip/hip_runtime.h>

// ---------------------------------------------------------------------------
// ROIAwareGCN: 3x GCNConv + mean-pool + MLP.
// R1: atomic pool -> segmented reduction over sorted batch.
// R2: split-bf16 MFMA GEMM (no LDS), bf16 t, gather ILP.
// R3: padded CSR (int4/float4, dummy wgt=0), bf16 h, fused preproc.
// R4: pool+mlp fused; 16-deep agg bursts; h3 bf16.
// R5/R6: k_scan -> coalesced 2-barrier single-block scan (~5us).
// R7: CSR build was 47-56us with 67MB WRITE (10x amplification: 4B scattered
//     stores, line ping-pong across XCDs). Now 2-phase counting sort:
//     k_bin scatters (s,d) int2 into per-bucket (dst>>7) contiguous bins
//     (L2-hot, dense write-back), k_csr2 stages each bucket's padded CSR
//     region in LDS (zero-init = padding), LDS-atomic row cursors, coalesced
//     writeout. No fill2, no pad-fill tail.
// ---------------------------------------------------------------------------

typedef __bf16 bf16x8 __attribute__((ext_vector_type(8)));
typedef float f32x4 __attribute__((ext_vector_type(4)));

__device__ __forceinline__ float bflo(unsigned u) { return __uint_as_float(u << 16); }
__device__ __forceinline__ float bfhi(unsigned u) { return __uint_as_float(u & 0xffff0000u); }

union BF2 {
    __bf16 h[2];
    unsigned u;
};

// ---------------- W pre-pack into MFMA B-fragment layout ----------------
__device__ __forceinline__ void wpack_block(const float* __restrict__ W,
                                            __bf16* __restrict__ hi,
                                            __bf16* __restrict__ lo, int N, int b, int l) {
    int t = b >> 2, c = b & 3;
    int k0 = c * 32 + (l >> 4) * 8;
    int ncol = t * 16 + (l & 15);
    size_t base = ((size_t)b * 64 + l) * 8;
#pragma unroll
    for (int j = 0; j < 8; j++) {
        float v = W[(size_t)(k0 + j) * N + ncol];
        __bf16 h = (__bf16)v;
        hi[base + j] = h;
        lo[base + j] = (__bf16)(v - (float)h);
    }
}

// ---------------- fused: degree count + graph boundaries + wpack(W1) ----------------
__global__ void k_pre(const int* __restrict__ dst, int* __restrict__ cnt,
                      const int* __restrict__ batch, int* __restrict__ gstart,
                      const float* __restrict__ W1, __bf16* __restrict__ Wp1h,
                      __bf16* __restrict__ Wp1l, int E, int n, int G, int EB) {
    int b = blockIdx.x;
    if (b < EB) {
        int e = b * 256 + threadIdx.x;
        if (e < E) atomicAdd(&cnt[dst[e]], 1);
    } else if (b == EB) {
        int g = threadIdx.x;
        if (g <= G) {
            int lo = 0, hi = n;
            while (lo < hi) {
                int mid = (lo + hi) >> 1;
                if (batch[mid] < g) lo = mid + 1; else hi = mid;
            }
            gstart[g] = lo;  // lower_bound: first i with batch[i] >= g
        }
    } else {
        int b64 = (b - EB - 1) * 4 + (threadIdx.x >> 6);  // 0..31
        if (b64 < 32) wpack_block(W1, Wp1h, Wp1l, 128, b64, threadIdx.x & 63);
    }
}

// ---------------- 2-barrier single-block scan -> rowptr, dinv ----------------
// rowptr over PADDED counts ((c+3)&~3). Supports n <= 16*4096 = 65536.
__global__ __launch_bounds__(1024) void k_scan(const int* __restrict__ cnt,
                                               int* __restrict__ rowptr,
                                               float* __restrict__ dinv, int n) {
    __shared__ int lsum[16 * 16];  // [chunk][wave] totals -> exclusive prefixes
    __shared__ int tot_s;
    int tid = threadIdx.x;
    int lane = tid & 63;
    int wid = tid >> 6;
    int chunks = (n + 4095) >> 12;  // <= 16
    int exc[16];

    // Phase A: per-chunk coalesced load, dinv, wave-scan; no barriers.
    for (int c = 0; c < chunks; c++) {
        int i0 = (c << 12) + tid * 4;
        int s = 0;
        if (i0 + 3 < n) {
            int4 v = *(const int4*)(cnt + i0);
            float4 dv;
            dv.x = rsqrtf((float)(v.x + 1));
            dv.y = rsqrtf((float)(v.y + 1));
            dv.z = rsqrtf((float)(v.z + 1));
            dv.w = rsqrtf((float)(v.w + 1));
            *(float4*)(dinv + i0) = dv;
            s = ((v.x + 3) & ~3) + ((v.y + 3) & ~3) + ((v.z + 3) & ~3) + ((v.w + 3) & ~3);
        } else if (i0 < n) {
#pragma unroll
            for (int j = 0; j < 4; j++) {
                if (i0 + j < n) {
                    int v = cnt[i0 + j];
                    dinv[i0 + j] = rsqrtf((float)(v + 1));
                    s += (v + 3) & ~3;
                }
            }
        }
        int sc = s;
#pragma unroll
        for (int d = 1; d < 64; d <<= 1) {
            int o = __shfl_up(sc, d);
            if (lane >= d) sc += o;
        }
        exc[c] = sc - s;  // exclusive prefix within wave
        if (lane == 63) lsum[c * 16 + wid] = sc;
    }
    __syncthreads();

    // Phase B: wave 0 scans chunk-major (chunk,wave) totals (<=256 entries).
    if (wid == 0) {
        int total = chunks * 16;
        int carry = 0;
        for (int base = 0; base < total; base += 64) {
            int idx = base + lane;
            int val = (idx < total) ? lsum[idx] : 0;
            int sc = val;
#pragma unroll
            for (int d = 1; d < 64; d <<= 1) {
                int o = __shfl_up(sc, d);
                if (lane >= d) sc += o;
            }
            int grp = __shfl(sc, 63);
            if (idx < total) lsum[idx] = sc - val + carry;
            carry += grp;
        }
        if (lane == 0) tot_s = carry;
    }
    __syncthreads();

    // Phase C: L2-hot reload, coalesced rowptr writes.
    for (int c = 0; c < chunks; c++) {
        int i0 = (c << 12) + tid * 4;
        if (i0 >= n) continue;
        int off = lsum[c * 16 + wid] + exc[c];
        if (i0 + 3 < n) {
            int4 v = *(const int4*)(cnt + i0);
            int o0 = off;
            int o1 = o0 + ((v.x + 3) & ~3);
            int o2 = o1 + ((v.y + 3) & ~3);
            int o3 = o2 + ((v.z + 3) & ~3);
            int4 ov = {o0, o1, o2, o3};
            *(int4*)(rowptr + i0) = ov;
        } else {
            int o = off;
#pragma unroll
            for (int j = 0; j < 4; j++) {
                if (i0 + j < n) {
                    rowptr[i0 + j] = o;
                    o += (cnt[i0 + j] + 3) & ~3;
                }
            }
        }
    }
    if (tid == 0) rowptr[n] = tot_s;
}

// ---------------- pass 1: bin edges by dst bucket (dst>>7) + wpack(W2,W3) ----------------
__global__ void k_bin(const int* __restrict__ src, const int* __restrict__ dst,
                      const int* __restrict__ rowptr, int* __restrict__ bcur,
                      int2* __restrict__ binbuf, int E, int EB,
                      const float* __restrict__ W2, const float* __restrict__ W3,
                      __bf16* __restrict__ Wp2h, __bf16* __restrict__ Wp2l,
                      __bf16* __restrict__ Wp3h, __bf16* __restrict__ Wp3l) {
    int b = blockIdx.x;
    if (b < EB) {
        int e = b * 256 + threadIdx.x;
        if (e >= E) return;
        int s = src[e], d = dst[e];
        int bk = d >> 7;
        int pos = rowptr[bk << 7] + atomicAdd(&bcur[bk], 1);
        int2 sd = {s, d};
        binbuf[pos] = sd;
        return;
    }
    int idx = b - EB;  // 0..11: weight packing (48 wave-blocks)
    int b64 = idx * 4 + (threadIdx.x >> 6);
    int l = threadIdx.x & 63;
    if (b64 < 32) wpack_block(W2, Wp2h, Wp2l, 128, b64, l);
    else if (b64 < 48) wpack_block(W3, Wp3h, Wp3l, 64, b64 - 32, l);
}

// ---------------- pass 2: bucket -> padded CSR via LDS staging ----------------
// One block per bucket of 128 rows. LDS zero-init covers padding slots.
__global__ __launch_bounds__(256) void k_csr2(const int2* __restrict__ binbuf,
                                              const int* __restrict__ rowptr,
                                              const int* __restrict__ bcur,
                                              const int* __restrict__ cnt,
                                              const float* __restrict__ dinv,
                                              int* __restrict__ col,
                                              float* __restrict__ wgt, int n) {
    __shared__ int cols[4096];
    __shared__ float wgts[4096];
    __shared__ int lfill[128];
    int b = blockIdx.x;
    int tid = threadIdx.x;
    int r0 = b << 7;
    int r1 = r0 + 128;
    if (r1 > n) r1 = n;
    int base = rowptr[r0];
    int end = rowptr[r1];
    int size = end - base;
    int nrows = r1 - r0;
    if (tid < nrows) lfill[tid] = rowptr[r0 + tid] - base;
    int cntb = bcur[b];
    if (size <= 4096) {
        for (int i = tid; i < size; i += 256) {
            cols[i] = 0;
            wgts[i] = 0.f;
        }
        __syncthreads();
        for (int i = tid; i < cntb; i += 256) {
            int2 sd = binbuf[base + i];
            int pos = atomicAdd(&lfill[sd.y - r0], 1);
            cols[pos] = sd.x;
            wgts[pos] = dinv[sd.x] * dinv[sd.y];
        }
        __syncthreads();
        for (int i = tid; i < size; i += 256) {
            col[base + i] = cols[i];
            wgt[base + i] = wgts[i];
        }
    } else {
        // fallback (statistically unreachable): direct global scatter + pad fill
        __syncthreads();
        for (int i = tid; i < cntb; i += 256) {
            int2 sd = binbuf[base + i];
            int pos = base + atomicAdd(&lfill[sd.y - r0], 1);
            col[pos] = sd.x;
            wgt[pos] = dinv[sd.x] * dinv[sd.y];
        }
        if (tid < nrows) {
            int r = r0 + tid;
            for (int p = rowptr[r] + cnt[r]; p < rowptr[r + 1]; p++) {
                col[p] = 0;
                wgt[p] = 0.f;
            }
        }
    }
}

// ---------------- MFMA GEMMs ----------------
// fp32 A (layer 1): hi/lo split, 3 mfma per K-chunk.
template <int NT>
__global__ __launch_bounds__(256) void k_gemm_f32(const float* __restrict__ A,
                                                  const __bf16* __restrict__ Wp_hi,
                                                  const __bf16* __restrict__ Wp_lo,
                                                  __bf16* __restrict__ Cbf, int n) {
    constexpr int N = NT * 16;
    int wave = (int)((blockIdx.x * 256u + threadIdx.x) >> 6);
    int lane = threadIdx.x & 63;
    int row0 = wave * 16;
    if (row0 >= n) return;
    int m = lane & 15;
    int q = lane >> 4;
    int row = row0 + m;
    if (row >= n) row = n - 1;
    const float* ap = A + (size_t)row * 128 + q * 8;
    bf16x8 ahi[4], alo[4];
#pragma unroll
    for (int c = 0; c < 4; c++) {
        float4 v0 = *(const float4*)(ap + c * 32);
        float4 v1 = *(const float4*)(ap + c * 32 + 4);
        float vv[8] = {v0.x, v0.y, v0.z, v0.w, v1.x, v1.y, v1.z, v1.w};
#pragma unroll
        for (int j = 0; j < 8; j++) {
            __bf16 h = (__bf16)vv[j];
            ahi[c][j] = h;
            alo[c][j] = (__bf16)(vv[j] - (float)h);
        }
    }
#pragma unroll
    for (int t = 0; t < NT; t++) {
        f32x4 acc = {0.f, 0.f, 0.f, 0.f};
#pragma unroll
        for (int c = 0; c < 4; c++) {
            size_t off = ((size_t)(t * 4 + c) * 64 + lane) * 8;
            bf16x8 bh = *(const bf16x8*)(Wp_hi + off);
            bf16x8 bl = *(const bf16x8*)(Wp_lo + off);
            acc = __builtin_amdgcn_mfma_f32_16x16x32_bf16(ahi[c], bh, acc, 0, 0, 0);
            acc = __builtin_amdgcn_mfma_f32_16x16x32_bf16(alo[c], bh, acc, 0, 0, 0);
            acc = __builtin_amdgcn_mfma_f32_16x16x32_bf16(ahi[c], bl, acc, 0, 0, 0);
        }
        int colx = t * 16 + m;
#pragma unroll
        for (int r = 0; r < 4; r++) {
            int orow = row0 + q * 4 + r;
            if (orow < n) Cbf[(size_t)orow * N + colx] = (__bf16)acc[r];
        }
    }
}

// bf16 A (layers 2/3): 2 mfma per K-chunk.
template <int NT>
__global__ __launch_bounds__(256) void k_gemm_bf16(const __bf16* __restrict__ A,
                                                   const __bf16* __restrict__ Wp_hi,
                                                   const __bf16* __restrict__ Wp_lo,
                                                   __bf16* __restrict__ Cbf, int n) {
    constexpr int N = NT * 16;
    int wave = (int)((blockIdx.x * 256u + threadIdx.x) >> 6);
    int lane = threadIdx.x & 63;
    int row0 = wave * 16;
    if (row0 >= n) return;
    int m = lane & 15;
    int q = lane >> 4;
    int row = row0 + m;
    if (row >= n) row = n - 1;
    const __bf16* ap = A + (size_t)row * 128 + q * 8;
    bf16x8 a[4];
#pragma unroll
    for (int c = 0; c < 4; c++) a[c] = *(const bf16x8*)(ap + c * 32);
#pragma unroll
    for (int t = 0; t < NT; t++) {
        f32x4 acc = {0.f, 0.f, 0.f, 0.f};
#pragma unroll
        for (int c = 0; c < 4; c++) {
            size_t off = ((size_t)(t * 4 + c) * 64 + lane) * 8;
            bf16x8 bh = *(const bf16x8*)(Wp_hi + off);
            bf16x8 bl = *(const bf16x8*)(Wp_lo + off);
            acc = __builtin_amdgcn_mfma_f32_16x16x32_bf16(a[c], bh, acc, 0, 0, 0);
            acc = __builtin_amdgcn_mfma_f32_16x16x32_bf16(a[c], bl, acc, 0, 0, 0);
        }
        int colx = t * 16 + m;
#pragma unroll
        for (int r = 0; r < 4; r++) {
            int orow = row0 + q * 4 + r;
            if (orow < n) Cbf[(size_t)orow * N + colx] = (__bf16)acc[r];
        }
    }
}

// ---------------- aggregation (padded CSR, 16/8/4-deep gather bursts) ----------------
#define AGG128_BODY(CVEC, WVEC)                                        \
    {                                                                  \
        unsigned u0 = t32[((size_t)CVEC.x << 6) + lane];               \
        unsigned u1 = t32[((size_t)CVEC.y << 6) + lane];               \
        unsigned u2 = t32[((size_t)CVEC.z << 6) + lane];               \
        unsigned u3 = t32[((size_t)CVEC.w << 6) + lane];               \
        a0 += WVEC.x * bflo(u0); a1 += WVEC.x * bfhi(u0);              \
        a0 += WVEC.y * bflo(u1); a1 += WVEC.y * bfhi(u1);              \
        a0 += WVEC.z * bflo(u2); a1 += WVEC.z * bfhi(u2);              \
        a0 += WVEC.w * bflo(u3); a1 += WVEC.w * bfhi(u3);              \
    }

__global__ __launch_bounds__(256) void k_agg128(const unsigned int* __restrict__ t32,
                                                const int* __restrict__ rowptr,
                                                const int* __restrict__ col,
                                                const float* __restrict__ wgt,
                                                const float* __restrict__ dinv,
                                                const float* __restrict__ bias,
                                                unsigned int* __restrict__ out, int n) {
    int w = (int)((blockIdx.x * 256u + threadIdx.x) >> 6);
    int lane = threadIdx.x & 63;
    if (w >= n) return;
    float di = dinv[w];
    float sw = di * di;
    unsigned us = t32[(size_t)w * 64 + lane];
    float a0 = sw * bflo(us);
    float a1 = sw * bfhi(us);
    int p = rowptr[w], pe = rowptr[w + 1];
    for (; p + 16 <= pe; p += 16) {  // 16 gathers in flight
        int4 c0 = *(const int4*)(col + p);
        int4 c1 = *(const int4*)(col + p + 4);
        int4 c2 = *(const int4*)(col + p + 8);
        int4 c3 = *(const int4*)(col + p + 12);
        float4 w0 = *(const float4*)(wgt + p);
        float4 w1 = *(const float4*)(wgt + p + 4);
        float4 w2 = *(const float4*)(wgt + p + 8);
        float4 w3 = *(const float4*)(wgt + p + 12);
        unsigned u0 = t32[((size_t)c0.x << 6) + lane];
        unsigned u1 = t32[((size_t)c0.y << 6) + lane];
        unsigned u2 = t32[((size_t)c0.z << 6) + lane];
        unsigned u3 = t32[((size_t)c0.w << 6) + lane];
        unsigned u4 = t32[((size_t)c1.x << 6) + lane];
        unsigned u5 = t32[((size_t)c1.y << 6) + lane];
        unsigned u6 = t32[((size_t)c1.z << 6) + lane];
        unsigned u7 = t32[((size_t)c1.w << 6) + lane];
        unsigned u8 = t32[((size_t)c2.x << 6) + lane];
        unsigned u9 = t32[((size_t)c2.y << 6) + lane];
        unsigned ua = t32[((size_t)c2.z << 6) + lane];
        unsigned ub = t32[((size_t)c2.w << 6) + lane];
        unsigned uc = t32[((size_t)c3.x << 6) + lane];
        unsigned ud = t32[((size_t)c3.y << 6) + lane];
        unsigned ue = t32[((size_t)c3.z << 6) + lane];
        unsigned uf = t32[((size_t)c3.w << 6) + lane];
        a0 += w0.x * bflo(u0); a1 += w0.x * bfhi(u0);
        a0 += w0.y * bflo(u1); a1 += w0.y * bfhi(u1);
        a0 += w0.z * bflo(u2); a1 += w0.z * bfhi(u2);
        a0 += w0.w * bflo(u3); a1 += w0.w * bfhi(u3);
        a0 += w1.x * bflo(u4); a1 += w1.x * bfhi(u4);
        a0 += w1.y * bflo(u5); a1 += w1.y * bfhi(u5);
        a0 += w1.z * bflo(u6); a1 += w1.z * bfhi(u6);
        a0 += w1.w * bflo(u7); a1 += w1.w * bfhi(u7);
        a0 += w2.x * bflo(u8); a1 += w2.x * bfhi(u8);
        a0 += w2.y * bflo(u9); a1 += w2.y * bfhi(u9);
        a0 += w2.z * bflo(ua); a1 += w2.z * bfhi(ua);
        a0 += w2.w * bflo(ub); a1 += w2.w * bfhi(ub);
        a0 += w3.x * bflo(uc); a1 += w3.x * bfhi(uc);
        a0 += w3.y * bflo(ud); a1 += w3.y * bfhi(ud);
        a0 += w3.z * bflo(ue); a1 += w3.z * bfhi(ue);
        a0 += w3.w * bflo(uf); a1 += w3.w * bfhi(uf);
    }
    for (; p + 8 <= pe; p += 8) {
        int4 c0 = *(const int4*)(col + p);
        int4 c1 = *(const int4*)(col + p + 4);
        float4 w0 = *(const float4*)(wgt + p);
        float4 w1 = *(const float4*)(wgt + p + 4);
        AGG128_BODY(c0, w0)
        AGG128_BODY(c1, w1)
    }
    if (p < pe) {
        int4 c0 = *(const int4*)(col + p);
        float4 w0 = *(const float4*)(wgt + p);
        AGG128_BODY(c0, w0)
    }
    BF2 o;
    o.h[0] = (__bf16)fmaxf(a0 + bias[lane * 2], 0.f);
    o.h[1] = (__bf16)fmaxf(a1 + bias[lane * 2 + 1], 0.f);
    out[(size_t)w * 64 + lane] = o.u;
}

__global__ __launch_bounds__(256) void k_agg64(const unsigned short* __restrict__ t16,
                                               const int* __restrict__ rowptr,
                                               const int* __restrict__ col,
                                               const float* __restrict__ wgt,
                                               const float* __restrict__ dinv,
                                               const float* __restrict__ bias,
                                               __bf16* __restrict__ out, int n) {
    int w = (int)((blockIdx.x * 256u + threadIdx.x) >> 6);
    int lane = threadIdx.x & 63;
    if (w >= n) return;
    float di = dinv[w];
    float sw = di * di;
    float acc = sw * __uint_as_float((unsigned)t16[(size_t)w * 64 + lane] << 16);
    int p = rowptr[w], pe = rowptr[w + 1];
    for (; p + 16 <= pe; p += 16) {
        int4 c0 = *(const int4*)(col + p);
        int4 c1 = *(const int4*)(col + p + 4);
        int4 c2 = *(const int4*)(col + p + 8);
        int4 c3 = *(const int4*)(col + p + 12);
        float4 w0 = *(const float4*)(wgt + p);
        float4 w1 = *(const float4*)(wgt + p + 4);
        float4 w2 = *(const float4*)(wgt + p + 8);
        float4 w3 = *(const float4*)(wgt + p + 12);
        unsigned u0 = t16[((size_t)c0.x << 6) + lane];
        unsigned u1 = t16[((size_t)c0.y << 6) + lane];
        unsigned u2 = t16[((size_t)c0.z << 6) + lane];
        unsigned u3 = t16[((size_t)c0.w << 6) + lane];
        unsigned u4 = t16[((size_t)c1.x << 6) + lane];
        unsigned u5 = t16[((size_t)c1.y << 6) + lane];
        unsigned u6 = t16[((size_t)c1.z << 6) + lane];
        unsigned u7 = t16[((size_t)c1.w << 6) + lane];
        unsigned u8 = t16[((size_t)c2.x << 6) + lane];
        unsigned u9 = t16[((size_t)c2.y << 6) + lane];
        unsigned ua = t16[((size_t)c2.z << 6) + lane];
        unsigned ub = t16[((size_t)c2.w << 6) + lane];
        unsigned uc = t16[((size_t)c3.x << 6) + lane];
        unsigned ud = t16[((size_t)c3.y << 6) + lane];
        unsigned ue = t16[((size_t)c3.z << 6) + lane];
        unsigned uf = t16[((size_t)c3.w << 6) + lane];
        acc += w0.x * __uint_as_float(u0 << 16);
        acc += w0.y * __uint_as_float(u1 << 16);
        acc += w0.z * __uint_as_float(u2 << 16);
        acc += w0.w * __uint_as_float(u3 << 16);
        acc += w1.x * __uint_as_float(u4 << 16);
        acc += w1.y * __uint_as_float(u5 << 16);
        acc += w1.z * __uint_as_float(u6 << 16);
        acc += w1.w * __uint_as_float(u7 << 16);
        acc += w2.x * __uint_as_float(u8 << 16);
        acc += w2.y * __uint_as_float(u9 << 16);
        acc += w2.z * __uint_as_float(ua << 16);
        acc += w2.w * __uint_as_float(ub << 16);
        acc += w3.x * __uint_as_float(uc << 16);
        acc += w3.y * __uint_as_float(ud << 16);
        acc += w3.z * __uint_as_float(ue << 16);
        acc += w3.w * __uint_as_float(uf << 16);
    }
    for (; p + 4 <= pe; p += 4) {
        int4 c0 = *(const int4*)(col + p);
        float4 w0 = *(const float4*)(wgt + p);
        unsigned u0 = t16[((size_t)c0.x << 6) + lane];
        unsigned u1 = t16[((size_t)c0.y << 6) + lane];
        unsigned u2 = t16[((size_t)c0.z << 6) + lane];
        unsigned u3 = t16[((size_t)c0.w << 6) + lane];
        acc += w0.x * __uint_as_float(u0 << 16);
        acc += w0.y * __uint_as_float(u1 << 16);
        acc += w0.z * __uint_as_float(u2 << 16);
        acc += w0.w * __uint_as_float(u3 << 16);
    }
    out[(size_t)w * 64 + lane] = (__bf16)fmaxf(acc + bias[lane], 0.f);
}

// ---------------- fused mean-pool + MLP head ----------------
__global__ __launch_bounds__(256) void k_poolmlp(const unsigned short* __restrict__ h,
                                                 const int* __restrict__ gstart,
                                                 const float* __restrict__ demo,
                                                 const float* __restrict__ Wf1,
                                                 const float* __restrict__ bf1,
                                                 const float* __restrict__ Wf2,
                                                 const float* __restrict__ bf2,
                                                 const float* __restrict__ Wf3,
                                                 const float* __restrict__ bf3,
                                                 float* __restrict__ out, int G) {
    int g = blockIdx.x;
    int tid = threadIdx.x;
    int lane = tid & 63;
    int wv = tid >> 6;
    int s = gstart[g], e = gstart[g + 1];
    float acc = 0.f;
    for (int i = s + wv; i < e; i += 4)
        acc += __uint_as_float((unsigned)h[(size_t)i * 64 + lane] << 16);
    __shared__ float red[4][64];
    __shared__ float zin[72];
    __shared__ float z1[64];
    __shared__ float z2[32];
    red[wv][lane] = acc;
    if (tid >= 64 && tid < 72) zin[tid] = demo[g * 8 + (tid - 64)];
    __syncthreads();
    if (tid < 64) {
        float v = red[0][tid] + red[1][tid] + red[2][tid] + red[3][tid];
        zin[tid] = v / fmaxf((float)(e - s), 1.0f);
    }
    __syncthreads();
    if (tid < 64) {
        float a = bf1[tid];
        for (int k = 0; k < 72; k++) a += zin[k] * Wf1[k * 64 + tid];
        z1[tid] = fmaxf(a, 0.f);
    }
    __syncthreads();
    if (tid < 32) {
        float a2 = bf2[tid];
        for (int k = 0; k < 64; k++) a2 += z1[k] * Wf2[k * 32 + tid];
        z2[tid] = fmaxf(a2, 0.f);
    }
    __syncthreads();
    if (tid < 2) {
        float a3 = bf3[tid];
        for (int k = 0; k < 32; k++) a3 += z2[k] * Wf3[k * 2 + tid];
        out[g * 2 + tid] = a3;
    }
}

extern "C" void kernel_launch(void* const* d_in, const int* in_sizes, int n_in,
                              void* d_out, int out_size, void* d_ws, size_t ws_size,
                              hipStream_t stream) {
    const float* x    = (const float*)d_in[0];
    const int*   ei   = (const int*)d_in[1];
    const int*   batch= (const int*)d_in[2];
    const float* demo = (const float*)d_in[3];
    const float* W1   = (const float*)d_in[4];
    const float* b1   = (const float*)d_in[5];
    const float* W2   = (const float*)d_in[6];
    const float* b2   = (const float*)d_in[7];
    const float* W3   = (const float*)d_in[8];
    const float* b3   = (const float*)d_in[9];
    const float* Wf1  = (const float*)d_in[10];
    const float* bf1  = (const float*)d_in[11];
    const float* Wf2  = (const float*)d_in[12];
    const float* bf2  = (const float*)d_in[13];
    const float* Wf3  = (const float*)d_in[14];
    const float* bf3  = (const float*)d_in[15];
    float* out = (float*)d_out;

    const int n = in_sizes[0] / 128;  // 50000
    const int E = in_sizes[1] / 2;    // 600000
    const int G = in_sizes[3] / 8;    // 100
    const int Epad = E + 3 * n;       // worst-case padded CSR size
    const int nbuck = (n + 127) / 128;

    char* ws = (char*)d_ws;
    auto alloc = [&](size_t bytes) {
        char* p = ws;
        ws += (bytes + 255) & ~(size_t)255;
        return p;
    };
    int*    cnt    = (int*)alloc((size_t)n * 4);
    int*    bcur   = (int*)alloc((size_t)nbuck * 4);   // adjacent to cnt: one memset
    float*  dinv   = (float*)alloc((size_t)n * 4);
    int*    rowptr = (int*)alloc((size_t)(n + 1) * 4);
    int*    col    = (int*)alloc((size_t)Epad * 4);
    float*  wgt    = (float*)alloc((size_t)Epad * 4);
    int2*   binbuf = (int2*)alloc((size_t)Epad * 8);
    __bf16* tbf    = (__bf16*)alloc((size_t)n * 128 * 2);  // GEMM out bf16 (layers 1/2)
    __bf16* hbuf   = (__bf16*)alloc((size_t)n * 128 * 2);  // agg out bf16
    __bf16* t3bf   = (__bf16*)alloc((size_t)n * 64 * 2);   // GEMM3 out
    __bf16* h3     = (__bf16*)alloc((size_t)n * 64 * 2);   // agg3 out (bf16)
    __bf16* Wp1h   = (__bf16*)alloc(128 * 128 * 2);
    __bf16* Wp1l   = (__bf16*)alloc(128 * 128 * 2);
    __bf16* Wp2h   = (__bf16*)alloc(128 * 128 * 2);
    __bf16* Wp2l   = (__bf16*)alloc(128 * 128 * 2);
    __bf16* Wp3h   = (__bf16*)alloc(128 * 64 * 2);
    __bf16* Wp3l   = (__bf16*)alloc(128 * 64 * 2);
    int*    gstart = (int*)alloc((size_t)(G + 1) * 4);

    const int* srcv = ei;
    const int* dstv = ei + E;

    // cnt + bcur adjacent: one memset covers both.
    hipMemsetAsync(cnt, 0, (size_t)((char*)bcur - (char*)cnt) + (size_t)nbuck * 4, stream);

    const int EB = (E + 255) / 256;
    // k_pre: EB degree blocks + 1 gstart block + 8 wpack(W1) blocks
    k_pre<<<EB + 9, 256, 0, stream>>>(dstv, cnt, batch, gstart, W1, Wp1h, Wp1l, E, n, G, EB);
    k_scan<<<1, 1024, 0, stream>>>(cnt, rowptr, dinv, n);
    // pass 1: bin by dst bucket (+ wpack W2/W3)
    k_bin<<<EB + 12, 256, 0, stream>>>(srcv, dstv, rowptr, bcur, binbuf, E, EB,
                                       W2, W3, Wp2h, Wp2l, Wp3h, Wp3l);
    // pass 2: bucket -> padded CSR (LDS staging, coalesced writeout)
    k_csr2<<<nbuck, 256, 0, stream>>>(binbuf, rowptr, bcur, cnt, dinv, col, wgt, n);

    int waves = (n + 15) / 16;
    int gemm_blocks = (waves + 3) / 4;
    int agg_blocks = (int)(((size_t)n * 64 + 255) / 256);

    // Layer 1
    k_gemm_f32<8><<<gemm_blocks, 256, 0, stream>>>(x, Wp1h, Wp1l, tbf, n);
    k_agg128<<<agg_blocks, 256, 0, stream>>>((const unsigned int*)tbf, rowptr, col, wgt,
                                             dinv, b1, (unsigned int*)hbuf, n);
    // Layer 2
    k_gemm_bf16<8><<<gemm_blocks, 256, 0, stream>>>(hbuf, Wp2h, Wp2l, tbf, n);
    k_agg128<<<agg_blocks, 256, 0, stream>>>((const unsigned int*)tbf, rowptr, col, wgt,
                                             dinv, b2, (unsigned int*)hbuf, n);
    // Layer 3 (128 -> 64)
    k_gemm_bf16<4><<<gemm_blocks, 256, 0, stream>>>(hbuf, Wp3h, Wp3l, t3bf, n);
    k_agg64<<<agg_blocks, 256, 0, stream>>>((const unsigned short*)t3bf, rowptr, col, wgt,
                                            dinv, b3, h3, n);

    k_poolmlp<<<G, 256, 0, stream>>>((const unsigned short*)h3, gstart, demo,
                                     Wf1, bf1, Wf2, bf2, Wf3, bf3, out, G);
}

// Round 10
// 347.548 us; speedup vs baseline: 1.5149x; 1.5149x over previous
//
#include <hip/hip_runtime.h>

// ---------------------------------------------------------------------------
// ROIAwareGCN: 3x GCNConv + mean-pool + MLP.
// R1: atomic pool -> segmented reduction over sorted batch.
// R2: split-bf16 MFMA GEMM (no LDS), bf16 t, gather ILP.
// R3: padded CSR (int4/float4, dummy wgt=0), bf16 h, fused preproc.
// R4: pool+mlp fused; 16-deep agg bursts; h3 bf16.
// R5/R6: coalesced 2-barrier single-block scan.
// R7: bucket-atomic binning REGRESSED (1535 serialized atomics/address).
// R8: LDS counting sort CRASHED (GPU memory fault; unprovable staging scan).
// R9: restore R6's proven direct scatter but col-ONLY (halves scattered write
//     traffic, drops random dinv gathers); new k_wfill computes wgt + zeroes
//     padding with one wave/row (coalesced, dinv L2-hot). Rigor: after a
//     crash, take the verifiable half of the win.
// ---------------------------------------------------------------------------

typedef __bf16 bf16x8 __attribute__((ext_vector_type(8)));
typedef float f32x4 __attribute__((ext_vector_type(4)));

__device__ __forceinline__ float bflo(unsigned u) { return __uint_as_float(u << 16); }
__device__ __forceinline__ float bfhi(unsigned u) { return __uint_as_float(u & 0xffff0000u); }

union BF2 {
    __bf16 h[2];
    unsigned u;
};

// ---------------- W pre-pack into MFMA B-fragment layout ----------------
__device__ __forceinline__ void wpack_block(const float* __restrict__ W,
                                            __bf16* __restrict__ hi,
                                            __bf16* __restrict__ lo, int N, int b, int l) {
    int t = b >> 2, c = b & 3;
    int k0 = c * 32 + (l >> 4) * 8;
    int ncol = t * 16 + (l & 15);
    size_t base = ((size_t)b * 64 + l) * 8;
#pragma unroll
    for (int j = 0; j < 8; j++) {
        float v = W[(size_t)(k0 + j) * N + ncol];
        __bf16 h = (__bf16)v;
        hi[base + j] = h;
        lo[base + j] = (__bf16)(v - (float)h);
    }
}

// ---- fused: degree count + graph boundaries + wpack(W1,W2,W3) ----
__global__ void k_pre(const int* __restrict__ dst, int* __restrict__ cnt,
                      const int* __restrict__ batch, int* __restrict__ gstart,
                      const float* __restrict__ W1, __bf16* __restrict__ Wp1h,
                      __bf16* __restrict__ Wp1l,
                      const float* __restrict__ W2, const float* __restrict__ W3,
                      __bf16* __restrict__ Wp2h, __bf16* __restrict__ Wp2l,
                      __bf16* __restrict__ Wp3h, __bf16* __restrict__ Wp3l,
                      int E, int n, int G, int EB) {
    int b = blockIdx.x;
    if (b < EB) {
        int e = b * 256 + threadIdx.x;
        if (e < E) atomicAdd(&cnt[dst[e]], 1);
    } else if (b == EB) {
        int g = threadIdx.x;
        if (g <= G) {
            int lo = 0, hi = n;
            while (lo < hi) {
                int mid = (lo + hi) >> 1;
                if (batch[mid] < g) lo = mid + 1; else hi = mid;
            }
            gstart[g] = lo;  // lower_bound: first i with batch[i] >= g
        }
    } else {
        int b64 = (b - EB - 1) * 4 + (threadIdx.x >> 6);  // 0..79
        int l = threadIdx.x & 63;
        if (b64 < 32) wpack_block(W1, Wp1h, Wp1l, 128, b64, l);
        else if (b64 < 64) wpack_block(W2, Wp2h, Wp2l, 128, b64 - 32, l);
        else if (b64 < 80) wpack_block(W3, Wp3h, Wp3l, 64, b64 - 64, l);
    }
}

// ---------------- 2-barrier single-block scan -> rowptr, fill2, dinv ----------------
// rowptr over PADDED counts ((c+3)&~3); fill2 = scatter cursor copy.
// Supports n <= 16*4096 = 65536.
__global__ __launch_bounds__(1024) void k_scan(const int* __restrict__ cnt,
                                               int* __restrict__ rowptr,
                                               int* __restrict__ fill2,
                                               float* __restrict__ dinv, int n) {
    __shared__ int lsum[16 * 16];
    __shared__ int tot_s;
    int tid = threadIdx.x;
    int lane = tid & 63;
    int wid = tid >> 6;
    int chunks = (n + 4095) >> 12;  // <= 16
    int exc[16];

    // Phase A: per-chunk coalesced load, dinv, wave-scan; no barriers.
    for (int c = 0; c < chunks; c++) {
        int i0 = (c << 12) + tid * 4;
        int s = 0;
        if (i0 + 3 < n) {
            int4 v = *(const int4*)(cnt + i0);
            float4 dv;
            dv.x = rsqrtf((float)(v.x + 1));
            dv.y = rsqrtf((float)(v.y + 1));
            dv.z = rsqrtf((float)(v.z + 1));
            dv.w = rsqrtf((float)(v.w + 1));
            *(float4*)(dinv + i0) = dv;
            s = ((v.x + 3) & ~3) + ((v.y + 3) & ~3) + ((v.z + 3) & ~3) + ((v.w + 3) & ~3);
        } else if (i0 < n) {
#pragma unroll
            for (int j = 0; j < 4; j++) {
                if (i0 + j < n) {
                    int v = cnt[i0 + j];
                    dinv[i0 + j] = rsqrtf((float)(v + 1));
                    s += (v + 3) & ~3;
                }
            }
        }
        int sc = s;
#pragma unroll
        for (int d = 1; d < 64; d <<= 1) {
            int o = __shfl_up(sc, d);
            if (lane >= d) sc += o;
        }
        exc[c] = sc - s;
        if (lane == 63) lsum[c * 16 + wid] = sc;
    }
    __syncthreads();

    // Phase B: wave 0 scans the (chunk,wave) totals; register carry broadcast.
    if (wid == 0) {
        int total = chunks * 16;
        int carry = 0;
        for (int base = 0; base < total; base += 64) {
            int idx = base + lane;
            int val = (idx < total) ? lsum[idx] : 0;
            int sc = val;
#pragma unroll
            for (int d = 1; d < 64; d <<= 1) {
                int o = __shfl_up(sc, d);
                if (lane >= d) sc += o;
            }
            int grp = __shfl(sc, 63);
            if (idx < total) lsum[idx] = sc - val + carry;
            carry += grp;
        }
        if (lane == 0) tot_s = carry;
    }
    __syncthreads();

    // Phase C: L2-hot reload, coalesced rowptr/fill2 writes.
    for (int c = 0; c < chunks; c++) {
        int i0 = (c << 12) + tid * 4;
        if (i0 >= n) continue;
        int off = lsum[c * 16 + wid] + exc[c];
        if (i0 + 3 < n) {
            int4 v = *(const int4*)(cnt + i0);
            int o0 = off;
            int o1 = o0 + ((v.x + 3) & ~3);
            int o2 = o1 + ((v.y + 3) & ~3);
            int o3 = o2 + ((v.z + 3) & ~3);
            int4 ov = {o0, o1, o2, o3};
            *(int4*)(rowptr + i0) = ov;
            *(int4*)(fill2 + i0) = ov;
        } else {
            int o = off;
#pragma unroll
            for (int j = 0; j < 4; j++) {
                if (i0 + j < n) {
                    rowptr[i0 + j] = o;
                    fill2[i0 + j] = o;
                    o += (cnt[i0 + j] + 3) & ~3;
                }
            }
        }
    }
    if (tid == 0) rowptr[n] = tot_s;
}

// ---------------- CSR scatter: col only (4B scattered writes, no gathers) ----------------
__global__ void k_csr(const int* __restrict__ src, const int* __restrict__ dst,
                      int* __restrict__ fill2, int* __restrict__ col, int E) {
    int e = blockIdx.x * blockDim.x + threadIdx.x;
    if (e >= E) return;
    int pos = atomicAdd(&fill2[dst[e]], 1);
    col[pos] = src[e];
}

// ---------------- wgt compute + padding zero: one wave per row, coalesced ----------------
__global__ __launch_bounds__(256) void k_wfill(const int* __restrict__ rowptr,
                                               const int* __restrict__ cnt,
                                               const float* __restrict__ dinv,
                                               int* __restrict__ col,
                                               float* __restrict__ wgt, int n) {
    int w = (int)((blockIdx.x * 256u + threadIdx.x) >> 6);
    int lane = threadIdx.x & 63;
    if (w >= n) return;
    int p0 = rowptr[w], p1 = rowptr[w + 1];
    int pv = p0 + cnt[w];
    float dw = dinv[w];
    for (int p = p0 + lane; p < p1; p += 64) {
        if (p < pv) {
            wgt[p] = dinv[col[p]] * dw;
        } else {
            col[p] = 0;
            wgt[p] = 0.f;
        }
    }
}

// ---------------- MFMA GEMMs ----------------
template <int NT>
__global__ __launch_bounds__(256) void k_gemm_f32(const float* __restrict__ A,
                                                  const __bf16* __restrict__ Wp_hi,
                                                  const __bf16* __restrict__ Wp_lo,
                                                  __bf16* __restrict__ Cbf, int n) {
    constexpr int N = NT * 16;
    int wave = (int)((blockIdx.x * 256u + threadIdx.x) >> 6);
    int lane = threadIdx.x & 63;
    int row0 = wave * 16;
    if (row0 >= n) return;
    int m = lane & 15;
    int q = lane >> 4;
    int row = row0 + m;
    if (row >= n) row = n - 1;
    const float* ap = A + (size_t)row * 128 + q * 8;
    bf16x8 ahi[4], alo[4];
#pragma unroll
    for (int c = 0; c < 4; c++) {
        float4 v0 = *(const float4*)(ap + c * 32);
        float4 v1 = *(const float4*)(ap + c * 32 + 4);
        float vv[8] = {v0.x, v0.y, v0.z, v0.w, v1.x, v1.y, v1.z, v1.w};
#pragma unroll
        for (int j = 0; j < 8; j++) {
            __bf16 h = (__bf16)vv[j];
            ahi[c][j] = h;
            alo[c][j] = (__bf16)(vv[j] - (float)h);
        }
    }
#pragma unroll
    for (int t = 0; t < NT; t++) {
        f32x4 acc = {0.f, 0.f, 0.f, 0.f};
#pragma unroll
        for (int c = 0; c < 4; c++) {
            size_t off = ((size_t)(t * 4 + c) * 64 + lane) * 8;
            bf16x8 bh = *(const bf16x8*)(Wp_hi + off);
            bf16x8 bl = *(const bf16x8*)(Wp_lo + off);
            acc = __builtin_amdgcn_mfma_f32_16x16x32_bf16(ahi[c], bh, acc, 0, 0, 0);
            acc = __builtin_amdgcn_mfma_f32_16x16x32_bf16(alo[c], bh, acc, 0, 0, 0);
            acc = __builtin_amdgcn_mfma_f32_16x16x32_bf16(ahi[c], bl, acc, 0, 0, 0);
        }
        int colx = t * 16 + m;
#pragma unroll
        for (int r = 0; r < 4; r++) {
            int orow = row0 + q * 4 + r;
            if (orow < n) Cbf[(size_t)orow * N + colx] = (__bf16)acc[r];
        }
    }
}

template <int NT>
__global__ __launch_bounds__(256) void k_gemm_bf16(const __bf16* __restrict__ A,
                                                   const __bf16* __restrict__ Wp_hi,
                                                   const __bf16* __restrict__ Wp_lo,
                                                   __bf16* __restrict__ Cbf, int n) {
    constexpr int N = NT * 16;
    int wave = (int)((blockIdx.x * 256u + threadIdx.x) >> 6);
    int lane = threadIdx.x & 63;
    int row0 = wave * 16;
    if (row0 >= n) return;
    int m = lane & 15;
    int q = lane >> 4;
    int row = row0 + m;
    if (row >= n) row = n - 1;
    const __bf16* ap = A + (size_t)row * 128 + q * 8;
    bf16x8 a[4];
#pragma unroll
    for (int c = 0; c < 4; c++) a[c] = *(const bf16x8*)(ap + c * 32);
#pragma unroll
    for (int t = 0; t < NT; t++) {
        f32x4 acc = {0.f, 0.f, 0.f, 0.f};
#pragma unroll
        for (int c = 0; c < 4; c++) {
            size_t off = ((size_t)(t * 4 + c) * 64 + lane) * 8;
            bf16x8 bh = *(const bf16x8*)(Wp_hi + off);
            bf16x8 bl = *(const bf16x8*)(Wp_lo + off);
            acc = __builtin_amdgcn_mfma_f32_16x16x32_bf16(a[c], bh, acc, 0, 0, 0);
            acc = __builtin_amdgcn_mfma_f32_16x16x32_bf16(a[c], bl, acc, 0, 0, 0);
        }
        int colx = t * 16 + m;
#pragma unroll
        for (int r = 0; r < 4; r++) {
            int orow = row0 + q * 4 + r;
            if (orow < n) Cbf[(size_t)orow * N + colx] = (__bf16)acc[r];
        }
    }
}

// ---------------- aggregation (padded CSR, 16/8/4-deep gather bursts) ----------------
#define AGG128_BODY(CVEC, WVEC)                                        \
    {                                                                  \
        unsigned u0 = t32[((size_t)CVEC.x << 6) + lane];               \
        unsigned u1 = t32[((size_t)CVEC.y << 6) + lane];               \
        unsigned u2 = t32[((size_t)CVEC.z << 6) + lane];               \
        unsigned u3 = t32[((size_t)CVEC.w << 6) + lane];               \
        a0 += WVEC.x * bflo(u0); a1 += WVEC.x * bfhi(u0);              \
        a0 += WVEC.y * bflo(u1); a1 += WVEC.y * bfhi(u1);              \
        a0 += WVEC.z * bflo(u2); a1 += WVEC.z * bfhi(u2);              \
        a0 += WVEC.w * bflo(u3); a1 += WVEC.w * bfhi(u3);              \
    }

__global__ __launch_bounds__(256) void k_agg128(const unsigned int* __restrict__ t32,
                                                const int* __restrict__ rowptr,
                                                const int* __restrict__ col,
                                                const float* __restrict__ wgt,
                                                const float* __restrict__ dinv,
                                                const float* __restrict__ bias,
                                                unsigned int* __restrict__ out, int n) {
    int w = (int)((blockIdx.x * 256u + threadIdx.x) >> 6);
    int lane = threadIdx.x & 63;
    if (w >= n) return;
    float di = dinv[w];
    float sw = di * di;
    unsigned us = t32[(size_t)w * 64 + lane];
    float a0 = sw * bflo(us);
    float a1 = sw * bfhi(us);
    int p = rowptr[w], pe = rowptr[w + 1];
    for (; p + 16 <= pe; p += 16) {
        int4 c0 = *(const int4*)(col + p);
        int4 c1 = *(const int4*)(col + p + 4);
        int4 c2 = *(const int4*)(col + p + 8);
        int4 c3 = *(const int4*)(col + p + 12);
        float4 w0 = *(const float4*)(wgt + p);
        float4 w1 = *(const float4*)(wgt + p + 4);
        float4 w2 = *(const float4*)(wgt + p + 8);
        float4 w3 = *(const float4*)(wgt + p + 12);
        unsigned u0 = t32[((size_t)c0.x << 6) + lane];
        unsigned u1 = t32[((size_t)c0.y << 6) + lane];
        unsigned u2 = t32[((size_t)c0.z << 6) + lane];
        unsigned u3 = t32[((size_t)c0.w << 6) + lane];
        unsigned u4 = t32[((size_t)c1.x << 6) + lane];
        unsigned u5 = t32[((size_t)c1.y << 6) + lane];
        unsigned u6 = t32[((size_t)c1.z << 6) + lane];
        unsigned u7 = t32[((size_t)c1.w << 6) + lane];
        unsigned u8 = t32[((size_t)c2.x << 6) + lane];
        unsigned u9 = t32[((size_t)c2.y << 6) + lane];
        unsigned ua = t32[((size_t)c2.z << 6) + lane];
        unsigned ub = t32[((size_t)c2.w << 6) + lane];
        unsigned uc = t32[((size_t)c3.x << 6) + lane];
        unsigned ud = t32[((size_t)c3.y << 6) + lane];
        unsigned ue = t32[((size_t)c3.z << 6) + lane];
        unsigned uf = t32[((size_t)c3.w << 6) + lane];
        a0 += w0.x * bflo(u0); a1 += w0.x * bfhi(u0);
        a0 += w0.y * bflo(u1); a1 += w0.y * bfhi(u1);
        a0 += w0.z * bflo(u2); a1 += w0.z * bfhi(u2);
        a0 += w0.w * bflo(u3); a1 += w0.w * bfhi(u3);
        a0 += w1.x * bflo(u4); a1 += w1.x * bfhi(u4);
        a0 += w1.y * bflo(u5); a1 += w1.y * bfhi(u5);
        a0 += w1.z * bflo(u6); a1 += w1.z * bfhi(u6);
        a0 += w1.w * bflo(u7); a1 += w1.w * bfhi(u7);
        a0 += w2.x * bflo(u8); a1 += w2.x * bfhi(u8);
        a0 += w2.y * bflo(u9); a1 += w2.y * bfhi(u9);
        a0 += w2.z * bflo(ua); a1 += w2.z * bfhi(ua);
        a0 += w2.w * bflo(ub); a1 += w2.w * bfhi(ub);
        a0 += w3.x * bflo(uc); a1 += w3.x * bfhi(uc);
        a0 += w3.y * bflo(ud); a1 += w3.y * bfhi(ud);
        a0 += w3.z * bflo(ue); a1 += w3.z * bfhi(ue);
        a0 += w3.w * bflo(uf); a1 += w3.w * bfhi(uf);
    }
    for (; p + 8 <= pe; p += 8) {
        int4 c0 = *(const int4*)(col + p);
        int4 c1 = *(const int4*)(col + p + 4);
        float4 w0 = *(const float4*)(wgt + p);
        float4 w1 = *(const float4*)(wgt + p + 4);
        AGG128_BODY(c0, w0)
        AGG128_BODY(c1, w1)
    }
    if (p < pe) {
        int4 c0 = *(const int4*)(col + p);
        float4 w0 = *(const float4*)(wgt + p);
        AGG128_BODY(c0, w0)
    }
    BF2 o;
    o.h[0] = (__bf16)fmaxf(a0 + bias[lane * 2], 0.f);
    o.h[1] = (__bf16)fmaxf(a1 + bias[lane * 2 + 1], 0.f);
    out[(size_t)w * 64 + lane] = o.u;
}

__global__ __launch_bounds__(256) void k_agg64(const unsigned short* __restrict__ t16,
                                               const int* __restrict__ rowptr,
                                               const int* __restrict__ col,
                                               const float* __restrict__ wgt,
                                               const float* __restrict__ dinv,
                                               const float* __restrict__ bias,
                                               __bf16* __restrict__ out, int n) {
    int w = (int)((blockIdx.x * 256u + threadIdx.x) >> 6);
    int lane = threadIdx.x & 63;
    if (w >= n) return;
    float di = dinv[w];
    float sw = di * di;
    float acc = sw * __uint_as_float((unsigned)t16[(size_t)w * 64 + lane] << 16);
    int p = rowptr[w], pe = rowptr[w + 1];
    for (; p + 16 <= pe; p += 16) {
        int4 c0 = *(const int4*)(col + p);
        int4 c1 = *(const int4*)(col + p + 4);
        int4 c2 = *(const int4*)(col + p + 8);
        int4 c3 = *(const int4*)(col + p + 12);
        float4 w0 = *(const float4*)(wgt + p);
        float4 w1 = *(const float4*)(wgt + p + 4);
        float4 w2 = *(const float4*)(wgt + p + 8);
        float4 w3 = *(const float4*)(wgt + p + 12);
        unsigned u0 = t16[((size_t)c0.x << 6) + lane];
        unsigned u1 = t16[((size_t)c0.y << 6) + lane];
        unsigned u2 = t16[((size_t)c0.z << 6) + lane];
        unsigned u3 = t16[((size_t)c0.w << 6) + lane];
        unsigned u4 = t16[((size_t)c1.x << 6) + lane];
        unsigned u5 = t16[((size_t)c1.y << 6) + lane];
        unsigned u6 = t16[((size_t)c1.z << 6) + lane];
        unsigned u7 = t16[((size_t)c1.w << 6) + lane];
        unsigned u8 = t16[((size_t)c2.x << 6) + lane];
        unsigned u9 = t16[((size_t)c2.y << 6) + lane];
        unsigned ua = t16[((size_t)c2.z << 6) + lane];
        unsigned ub = t16[((size_t)c2.w << 6) + lane];
        unsigned uc = t16[((size_t)c3.x << 6) + lane];
        unsigned ud = t16[((size_t)c3.y << 6) + lane];
        unsigned ue = t16[((size_t)c3.z << 6) + lane];
        unsigned uf = t16[((size_t)c3.w << 6) + lane];
        acc += w0.x * __uint_as_float(u0 << 16);
        acc += w0.y * __uint_as_float(u1 << 16);
        acc += w0.z * __uint_as_float(u2 << 16);
        acc += w0.w * __uint_as_float(u3 << 16);
        acc += w1.x * __uint_as_float(u4 << 16);
        acc += w1.y * __uint_as_float(u5 << 16);
        acc += w1.z * __uint_as_float(u6 << 16);
        acc += w1.w * __uint_as_float(u7 << 16);
        acc += w2.x * __uint_as_float(u8 << 16);
        acc += w2.y * __uint_as_float(u9 << 16);
        acc += w2.z * __uint_as_float(ua << 16);
        acc += w2.w * __uint_as_float(ub << 16);
        acc += w3.x * __uint_as_float(uc << 16);
        acc += w3.y * __uint_as_float(ud << 16);
        acc += w3.z * __uint_as_float(ue << 16);
        acc += w3.w * __uint_as_float(uf << 16);
    }
    for (; p + 4 <= pe; p += 4) {
        int4 c0 = *(const int4*)(col + p);
        float4 w0 = *(const float4*)(wgt + p);
        unsigned u0 = t16[((size_t)c0.x << 6) + lane];
        unsigned u1 = t16[((size_t)c0.y << 6) + lane];
        unsigned u2 = t16[((size_t)c0.z << 6) + lane];
        unsigned u3 = t16[((size_t)c0.w << 6) + lane];
        acc += w0.x * __uint_as_float(u0 << 16);
        acc += w0.y * __uint_as_float(u1 << 16);
        acc += w0.z * __uint_as_float(u2 << 16);
        acc += w0.w * __uint_as_float(u3 << 16);
    }
    out[(size_t)w * 64 + lane] = (__bf16)fmaxf(acc + bias[lane], 0.f);
}

// ---------------- fused mean-pool + MLP head ----------------
__global__ __launch_bounds__(256) void k_poolmlp(const unsigned short* __restrict__ h,
                                                 const int* __restrict__ gstart,
                                                 const float* __restrict__ demo,
                                                 const float* __restrict__ Wf1,
                                                 const float* __restrict__ bf1,
                                                 const float* __restrict__ Wf2,
                                                 const float* __restrict__ bf2,
                                                 const float* __restrict__ Wf3,
                                                 const float* __restrict__ bf3,
                                                 float* __restrict__ out, int G) {
    int g = blockIdx.x;
    int tid = threadIdx.x;
    int lane = tid & 63;
    int wv = tid >> 6;
    int s = gstart[g], e = gstart[g + 1];
    float acc = 0.f;
    for (int i = s + wv; i < e; i += 4)
        acc += __uint_as_float((unsigned)h[(size_t)i * 64 + lane] << 16);
    __shared__ float red[4][64];
    __shared__ float zin[72];
    __shared__ float z1[64];
    __shared__ float z2[32];
    red[wv][lane] = acc;
    if (tid >= 64 && tid < 72) zin[tid] = demo[g * 8 + (tid - 64)];
    __syncthreads();
    if (tid < 64) {
        float v = red[0][tid] + red[1][tid] + red[2][tid] + red[3][tid];
        zin[tid] = v / fmaxf((float)(e - s), 1.0f);
    }
    __syncthreads();
    if (tid < 64) {
        float a = bf1[tid];
        for (int k = 0; k < 72; k++) a += zin[k] * Wf1[k * 64 + tid];
        z1[tid] = fmaxf(a, 0.f);
    }
    __syncthreads();
    if (tid < 32) {
        float a2 = bf2[tid];
        for (int k = 0; k < 64; k++) a2 += z1[k] * Wf2[k * 32 + tid];
        z2[tid] = fmaxf(a2, 0.f);
    }
    __syncthreads();
    if (tid < 2) {
        float a3 = bf3[tid];
        for (int k = 0; k < 32; k++) a3 += z2[k] * Wf3[k * 2 + tid];
        out[g * 2 + tid] = a3;
    }
}

extern "C" void kernel_launch(void* const* d_in, const int* in_sizes, int n_in,
                              void* d_out, int out_size, void* d_ws, size_t ws_size,
                              hipStream_t stream) {
    const float* x    = (const float*)d_in[0];
    const int*   ei   = (const int*)d_in[1];
    const int*   batch= (const int*)d_in[2];
    const float* demo = (const float*)d_in[3];
    const float* W1   = (const float*)d_in[4];
    const float* b1   = (const float*)d_in[5];
    const float* W2   = (const float*)d_in[6];
    const float* b2   = (const float*)d_in[7];
    const float* W3   = (const float*)d_in[8];
    const float* b3   = (const float*)d_in[9];
    const float* Wf1  = (const float*)d_in[10];
    const float* bf1  = (const float*)d_in[11];
    const float* Wf2  = (const float*)d_in[12];
    const float* bf2  = (const float*)d_in[13];
    const float* Wf3  = (const float*)d_in[14];
    const float* bf3  = (const float*)d_in[15];
    float* out = (float*)d_out;

    const int n = in_sizes[0] / 128;  // 50000
    const int E = in_sizes[1] / 2;    // 600000
    const int G = in_sizes[3] / 8;    // 100
    const int Epad = E + 3 * n;       // worst-case padded CSR size

    char* ws = (char*)d_ws;
    auto alloc = [&](size_t bytes) {
        char* p = ws;
        ws += (bytes + 255) & ~(size_t)255;
        return p;
    };
    int*    cnt    = (int*)alloc((size_t)n * 4);
    float*  dinv   = (float*)alloc((size_t)n * 4);
    int*    rowptr = (int*)alloc((size_t)(n + 1) * 4);
    int*    fill2  = (int*)alloc((size_t)n * 4);   // scatter cursor (copy of rowptr)
    int*    col    = (int*)alloc((size_t)Epad * 4);
    float*  wgt    = (float*)alloc((size_t)Epad * 4);
    __bf16* tbf    = (__bf16*)alloc((size_t)n * 128 * 2);  // GEMM out bf16 (layers 1/2)
    __bf16* hbuf   = (__bf16*)alloc((size_t)n * 128 * 2);  // agg out bf16
    __bf16* t3bf   = (__bf16*)alloc((size_t)n * 64 * 2);   // GEMM3 out
    __bf16* h3     = (__bf16*)alloc((size_t)n * 64 * 2);   // agg3 out (bf16)
    __bf16* Wp1h   = (__bf16*)alloc(128 * 128 * 2);
    __bf16* Wp1l   = (__bf16*)alloc(128 * 128 * 2);
    __bf16* Wp2h   = (__bf16*)alloc(128 * 128 * 2);
    __bf16* Wp2l   = (__bf16*)alloc(128 * 128 * 2);
    __bf16* Wp3h   = (__bf16*)alloc(128 * 64 * 2);
    __bf16* Wp3l   = (__bf16*)alloc(128 * 64 * 2);
    int*    gstart = (int*)alloc((size_t)(G + 1) * 4);

    const int* srcv = ei;
    const int* dstv = ei + E;

    hipMemsetAsync(cnt, 0, (size_t)n * 4, stream);

    const int EB = (E + 255) / 256;
    // k_pre: EB degree blocks + 1 gstart block + 20 wpack blocks (W1,W2,W3)
    k_pre<<<EB + 21, 256, 0, stream>>>(dstv, cnt, batch, gstart, W1, Wp1h, Wp1l,
                                       W2, W3, Wp2h, Wp2l, Wp3h, Wp3l, E, n, G, EB);
    k_scan<<<1, 1024, 0, stream>>>(cnt, rowptr, fill2, dinv, n);
    // CSR scatter: col only (half the scattered bytes of R6's col+wgt)
    k_csr<<<EB, 256, 0, stream>>>(srcv, dstv, fill2, col, E);

    int agg_blocks = (int)(((size_t)n * 64 + 255) / 256);
    // wgt + padding fill: one wave per row, coalesced
    k_wfill<<<agg_blocks, 256, 0, stream>>>(rowptr, cnt, dinv, col, wgt, n);

    int waves = (n + 15) / 16;
    int gemm_blocks = (waves + 3) / 4;

    // Layer 1
    k_gemm_f32<8><<<gemm_blocks, 256, 0, stream>>>(x, Wp1h, Wp1l, tbf, n);
    k_agg128<<<agg_blocks, 256, 0, stream>>>((const unsigned int*)tbf, rowptr, col, wgt,
                                             dinv, b1, (unsigned int*)hbuf, n);
    // Layer 2
    k_gemm_bf16<8><<<gemm_blocks, 256, 0, stream>>>(hbuf, Wp2h, Wp2l, tbf, n);
    k_agg128<<<agg_blocks, 256, 0, stream>>>((const unsigned int*)tbf, rowptr, col, wgt,
                                             dinv, b2, (unsigned int*)hbuf, n);
    // Layer 3 (128 -> 64)
    k_gemm_bf16<4><<<gemm_blocks, 256, 0, stream>>>(hbuf, Wp3h, Wp3l, t3bf, n);
    k_agg64<<<agg_blocks, 256, 0, stream>>>((const unsigned short*)t3bf, rowptr, col, wgt,
                                            dinv, b3, h3, n);

    k_poolmlp<<<G, 256, 0, stream>>>((const unsigned short*)h3, gstart, demo,
                                     Wf1, bf1, Wf2, bf2, Wf3, bf3, out, G);
}

// Round 11
// 343.433 us; speedup vs baseline: 1.5330x; 1.0120x over previous
//
#include <hip/hip_runtime.h>

// ---------------------------------------------------------------------------
// ROIAwareGCN: 3x GCNConv + mean-pool + MLP.
// R1: atomic pool -> segmented reduction over sorted batch.
// R2: split-bf16 MFMA GEMM (no LDS), bf16 t, gather ILP.
// R3: padded CSR (int4), bf16 h, fused preproc.
// R4: pool+mlp fused; 16-deep agg bursts; h3 bf16.
// R5/R6: coalesced 2-barrier single-block scan.
// R7: bucket-atomic binning REGRESSED. R8: LDS counting sort CRASHED.
// R9: col-only scatter NEUTRAL (-lesson: scattered writes cost per LINE,
//     not per byte -- halving bytes didn't halve line traffic).
// R10: wgt[] eliminated algebraically: GEMM epilogue pre-scales rows by dinv
//     (ts = dinv (.) x@W), agg = pure gather-sum, out = relu(dinv_i*sum + b).
//     Padding cols -> zero row at index n (k_scan writes pad cols + zeroes
//     row n of tbf/t3bf). k_wfill deleted; 10 dispatches.
// ---------------------------------------------------------------------------

typedef __bf16 bf16x8 __attribute__((ext_vector_type(8)));
typedef float f32x4 __attribute__((ext_vector_type(4)));

__device__ __forceinline__ float bflo(unsigned u) { return __uint_as_float(u << 16); }
__device__ __forceinline__ float bfhi(unsigned u) { return __uint_as_float(u & 0xffff0000u); }

union BF2 {
    __bf16 h[2];
    unsigned u;
};

// ---------------- W pre-pack into MFMA B-fragment layout ----------------
__device__ __forceinline__ void wpack_block(const float* __restrict__ W,
                                            __bf16* __restrict__ hi,
                                            __bf16* __restrict__ lo, int N, int b, int l) {
    int t = b >> 2, c = b & 3;
    int k0 = c * 32 + (l >> 4) * 8;
    int ncol = t * 16 + (l & 15);
    size_t base = ((size_t)b * 64 + l) * 8;
#pragma unroll
    for (int j = 0; j < 8; j++) {
        float v = W[(size_t)(k0 + j) * N + ncol];
        __bf16 h = (__bf16)v;
        hi[base + j] = h;
        lo[base + j] = (__bf16)(v - (float)h);
    }
}

// ---- fused: degree count + graph boundaries + wpack(W1,W2,W3) ----
__global__ void k_pre(const int* __restrict__ dst, int* __restrict__ cnt,
                      const int* __restrict__ batch, int* __restrict__ gstart,
                      const float* __restrict__ W1, __bf16* __restrict__ Wp1h,
                      __bf16* __restrict__ Wp1l,
                      const float* __restrict__ W2, const float* __restrict__ W3,
                      __bf16* __restrict__ Wp2h, __bf16* __restrict__ Wp2l,
                      __bf16* __restrict__ Wp3h, __bf16* __restrict__ Wp3l,
                      int E, int n, int G, int EB) {
    int b = blockIdx.x;
    if (b < EB) {
        int e = b * 256 + threadIdx.x;
        if (e < E) atomicAdd(&cnt[dst[e]], 1);
    } else if (b == EB) {
        int g = threadIdx.x;
        if (g <= G) {
            int lo = 0, hi = n;
            while (lo < hi) {
                int mid = (lo + hi) >> 1;
                if (batch[mid] < g) lo = mid + 1; else hi = mid;
            }
            gstart[g] = lo;  // lower_bound: first i with batch[i] >= g
        }
    } else {
        int b64 = (b - EB - 1) * 4 + (threadIdx.x >> 6);  // 0..79
        int l = threadIdx.x & 63;
        if (b64 < 32) wpack_block(W1, Wp1h, Wp1l, 128, b64, l);
        else if (b64 < 64) wpack_block(W2, Wp2h, Wp2l, 128, b64 - 32, l);
        else if (b64 < 80) wpack_block(W3, Wp3h, Wp3l, 64, b64 - 64, l);
    }
}

// ---------------- 2-barrier single-block scan ----------------
// Outputs: rowptr (padded counts), fill2 (cursor copy), dinv, padding cols
// (col[pad slot] = n -> zero row), zeroed row n of tbf/t3bf.
// Supports n <= 16*4096 = 65536.
__global__ __launch_bounds__(1024) void k_scan(const int* __restrict__ cnt,
                                               int* __restrict__ rowptr,
                                               int* __restrict__ fill2,
                                               float* __restrict__ dinv,
                                               int* __restrict__ col,
                                               unsigned int* __restrict__ tz128,
                                               unsigned int* __restrict__ tz64,
                                               int n) {
    __shared__ int lsum[16 * 16];
    __shared__ int tot_s;
    int tid = threadIdx.x;
    int lane = tid & 63;
    int wid = tid >> 6;
    int chunks = (n + 4095) >> 12;  // <= 16
    int exc[16];

    // zero row n of the two gather targets (64 + 32 uints)
    if (tid < 64) tz128[(size_t)n * 64 + tid] = 0u;
    else if (tid < 96) tz64[(size_t)n * 32 + (tid - 64)] = 0u;

    // Phase A: per-chunk coalesced load, dinv, wave-scan; no barriers.
    for (int c = 0; c < chunks; c++) {
        int i0 = (c << 12) + tid * 4;
        int s = 0;
        if (i0 + 3 < n) {
            int4 v = *(const int4*)(cnt + i0);
            float4 dv;
            dv.x = rsqrtf((float)(v.x + 1));
            dv.y = rsqrtf((float)(v.y + 1));
            dv.z = rsqrtf((float)(v.z + 1));
            dv.w = rsqrtf((float)(v.w + 1));
            *(float4*)(dinv + i0) = dv;
            s = ((v.x + 3) & ~3) + ((v.y + 3) & ~3) + ((v.z + 3) & ~3) + ((v.w + 3) & ~3);
        } else if (i0 < n) {
#pragma unroll
            for (int j = 0; j < 4; j++) {
                if (i0 + j < n) {
                    int v = cnt[i0 + j];
                    dinv[i0 + j] = rsqrtf((float)(v + 1));
                    s += (v + 3) & ~3;
                }
            }
        }
        int sc = s;
#pragma unroll
        for (int d = 1; d < 64; d <<= 1) {
            int o = __shfl_up(sc, d);
            if (lane >= d) sc += o;
        }
        exc[c] = sc - s;
        if (lane == 63) lsum[c * 16 + wid] = sc;
    }
    __syncthreads();

    // Phase B: wave 0 scans the (chunk,wave) totals; register carry.
    if (wid == 0) {
        int total = chunks * 16;
        int carry = 0;
        for (int base = 0; base < total; base += 64) {
            int idx = base + lane;
            int val = (idx < total) ? lsum[idx] : 0;
            int sc = val;
#pragma unroll
            for (int d = 1; d < 64; d <<= 1) {
                int o = __shfl_up(sc, d);
                if (lane >= d) sc += o;
            }
            int grp = __shfl(sc, 63);
            if (idx < total) lsum[idx] = sc - val + carry;
            carry += grp;
        }
        if (lane == 0) tot_s = carry;
    }
    __syncthreads();

    // Phase C: L2-hot reload, coalesced rowptr/fill2 writes, pad-col writes.
    for (int c = 0; c < chunks; c++) {
        int i0 = (c << 12) + tid * 4;
        if (i0 >= n) continue;
        int off = lsum[c * 16 + wid] + exc[c];
        if (i0 + 3 < n) {
            int4 v = *(const int4*)(cnt + i0);
            int o0 = off;
            int o1 = o0 + ((v.x + 3) & ~3);
            int o2 = o1 + ((v.y + 3) & ~3);
            int o3 = o2 + ((v.z + 3) & ~3);
            int o4 = o3 + ((v.w + 3) & ~3);
            int4 ov = {o0, o1, o2, o3};
            *(int4*)(rowptr + i0) = ov;
            *(int4*)(fill2 + i0) = ov;
            for (int p = o0 + v.x; p < o1; p++) col[p] = n;
            for (int p = o1 + v.y; p < o2; p++) col[p] = n;
            for (int p = o2 + v.z; p < o3; p++) col[p] = n;
            for (int p = o3 + v.w; p < o4; p++) col[p] = n;
        } else {
            int o = off;
#pragma unroll
            for (int j = 0; j < 4; j++) {
                if (i0 + j < n) {
                    int v = cnt[i0 + j];
                    rowptr[i0 + j] = o;
                    fill2[i0 + j] = o;
                    int onext = o + ((v + 3) & ~3);
                    for (int p = o + v; p < onext; p++) col[p] = n;
                    o = onext;
                }
            }
        }
    }
    if (tid == 0) rowptr[n] = tot_s;
}

// ---------------- CSR scatter: col only ----------------
__global__ void k_csr(const int* __restrict__ src, const int* __restrict__ dst,
                      int* __restrict__ fill2, int* __restrict__ col, int E) {
    int e = blockIdx.x * blockDim.x + threadIdx.x;
    if (e >= E) return;
    int pos = atomicAdd(&fill2[dst[e]], 1);
    col[pos] = src[e];
}

// ---------------- MFMA GEMMs (epilogue scales row by dinv) ----------------
template <int NT>
__global__ __launch_bounds__(256) void k_gemm_f32(const float* __restrict__ A,
                                                  const __bf16* __restrict__ Wp_hi,
                                                  const __bf16* __restrict__ Wp_lo,
                                                  const float* __restrict__ dinv,
                                                  __bf16* __restrict__ Cbf, int n) {
    constexpr int N = NT * 16;
    int wave = (int)((blockIdx.x * 256u + threadIdx.x) >> 6);
    int lane = threadIdx.x & 63;
    int row0 = wave * 16;
    if (row0 >= n) return;
    int m = lane & 15;
    int q = lane >> 4;
    int row = row0 + m;
    if (row >= n) row = n - 1;
    const float* ap = A + (size_t)row * 128 + q * 8;
    bf16x8 ahi[4], alo[4];
#pragma unroll
    for (int c = 0; c < 4; c++) {
        float4 v0 = *(const float4*)(ap + c * 32);
        float4 v1 = *(const float4*)(ap + c * 32 + 4);
        float vv[8] = {v0.x, v0.y, v0.z, v0.w, v1.x, v1.y, v1.z, v1.w};
#pragma unroll
        for (int j = 0; j < 8; j++) {
            __bf16 h = (__bf16)vv[j];
            ahi[c][j] = h;
            alo[c][j] = (__bf16)(vv[j] - (float)h);
        }
    }
    float dscale[4];
#pragma unroll
    for (int r = 0; r < 4; r++) {
        int rr = row0 + q * 4 + r;
        dscale[r] = dinv[rr < n ? rr : (n - 1)];
    }
#pragma unroll
    for (int t = 0; t < NT; t++) {
        f32x4 acc = {0.f, 0.f, 0.f, 0.f};
#pragma unroll
        for (int c = 0; c < 4; c++) {
            size_t off = ((size_t)(t * 4 + c) * 64 + lane) * 8;
            bf16x8 bh = *(const bf16x8*)(Wp_hi + off);
            bf16x8 bl = *(const bf16x8*)(Wp_lo + off);
            acc = __builtin_amdgcn_mfma_f32_16x16x32_bf16(ahi[c], bh, acc, 0, 0, 0);
            acc = __builtin_amdgcn_mfma_f32_16x16x32_bf16(alo[c], bh, acc, 0, 0, 0);
            acc = __builtin_amdgcn_mfma_f32_16x16x32_bf16(ahi[c], bl, acc, 0, 0, 0);
        }
        int colx = t * 16 + m;
#pragma unroll
        for (int r = 0; r < 4; r++) {
            int orow = row0 + q * 4 + r;
            if (orow < n) Cbf[(size_t)orow * N + colx] = (__bf16)(acc[r] * dscale[r]);
        }
    }
}

template <int NT>
__global__ __launch_bounds__(256) void k_gemm_bf16(const __bf16* __restrict__ A,
                                                   const __bf16* __restrict__ Wp_hi,
                                                   const __bf16* __restrict__ Wp_lo,
                                                   const float* __restrict__ dinv,
                                                   __bf16* __restrict__ Cbf, int n) {
    constexpr int N = NT * 16;
    int wave = (int)((blockIdx.x * 256u + threadIdx.x) >> 6);
    int lane = threadIdx.x & 63;
    int row0 = wave * 16;
    if (row0 >= n) return;
    int m = lane & 15;
    int q = lane >> 4;
    int row = row0 + m;
    if (row >= n) row = n - 1;
    const __bf16* ap = A + (size_t)row * 128 + q * 8;
    bf16x8 a[4];
#pragma unroll
    for (int c = 0; c < 4; c++) a[c] = *(const bf16x8*)(ap + c * 32);
    float dscale[4];
#pragma unroll
    for (int r = 0; r < 4; r++) {
        int rr = row0 + q * 4 + r;
        dscale[r] = dinv[rr < n ? rr : (n - 1)];
    }
#pragma unroll
    for (int t = 0; t < NT; t++) {
        f32x4 acc = {0.f, 0.f, 0.f, 0.f};
#pragma unroll
        for (int c = 0; c < 4; c++) {
            size_t off = ((size_t)(t * 4 + c) * 64 + lane) * 8;
            bf16x8 bh = *(const bf16x8*)(Wp_hi + off);
            bf16x8 bl = *(const bf16x8*)(Wp_lo + off);
            acc = __builtin_amdgcn_mfma_f32_16x16x32_bf16(a[c], bh, acc, 0, 0, 0);
            acc = __builtin_amdgcn_mfma_f32_16x16x32_bf16(a[c], bl, acc, 0, 0, 0);
        }
        int colx = t * 16 + m;
#pragma unroll
        for (int r = 0; r < 4; r++) {
            int orow = row0 + q * 4 + r;
            if (orow < n) Cbf[(size_t)orow * N + colx] = (__bf16)(acc[r] * dscale[r]);
        }
    }
}

// ---------------- aggregation: pure gather-sum over pre-scaled ts ----------------
// out_i = relu( dinv_i * (ts_i + sum_p ts[col[p]]) + bias ); pad cols hit zero row n.
__global__ __launch_bounds__(256) void k_agg128(const unsigned int* __restrict__ t32,
                                                const int* __restrict__ rowptr,
                                                const int* __restrict__ col,
                                                const float* __restrict__ dinv,
                                                const float* __restrict__ bias,
                                                unsigned int* __restrict__ out, int n) {
    int w = (int)((blockIdx.x * 256u + threadIdx.x) >> 6);
    int lane = threadIdx.x & 63;
    if (w >= n) return;
    unsigned us = t32[(size_t)w * 64 + lane];
    float a0 = bflo(us);
    float a1 = bfhi(us);
    int p = rowptr[w], pe = rowptr[w + 1];
    for (; p + 16 <= pe; p += 16) {  // 16 gathers in flight
        int4 c0 = *(const int4*)(col + p);
        int4 c1 = *(const int4*)(col + p + 4);
        int4 c2 = *(const int4*)(col + p + 8);
        int4 c3 = *(const int4*)(col + p + 12);
        unsigned u0 = t32[((size_t)c0.x << 6) + lane];
        unsigned u1 = t32[((size_t)c0.y << 6) + lane];
        unsigned u2 = t32[((size_t)c0.z << 6) + lane];
        unsigned u3 = t32[((size_t)c0.w << 6) + lane];
        unsigned u4 = t32[((size_t)c1.x << 6) + lane];
        unsigned u5 = t32[((size_t)c1.y << 6) + lane];
        unsigned u6 = t32[((size_t)c1.z << 6) + lane];
        unsigned u7 = t32[((size_t)c1.w << 6) + lane];
        unsigned u8 = t32[((size_t)c2.x << 6) + lane];
        unsigned u9 = t32[((size_t)c2.y << 6) + lane];
        unsigned ua = t32[((size_t)c2.z << 6) + lane];
        unsigned ub = t32[((size_t)c2.w << 6) + lane];
        unsigned uc = t32[((size_t)c3.x << 6) + lane];
        unsigned ud = t32[((size_t)c3.y << 6) + lane];
        unsigned ue = t32[((size_t)c3.z << 6) + lane];
        unsigned uf = t32[((size_t)c3.w << 6) + lane];
        a0 += bflo(u0); a1 += bfhi(u0);
        a0 += bflo(u1); a1 += bfhi(u1);
        a0 += bflo(u2); a1 += bfhi(u2);
        a0 += bflo(u3); a1 += bfhi(u3);
        a0 += bflo(u4); a1 += bfhi(u4);
        a0 += bflo(u5); a1 += bfhi(u5);
        a0 += bflo(u6); a1 += bfhi(u6);
        a0 += bflo(u7); a1 += bfhi(u7);
        a0 += bflo(u8); a1 += bfhi(u8);
        a0 += bflo(u9); a1 += bfhi(u9);
        a0 += bflo(ua); a1 += bfhi(ua);
        a0 += bflo(ub); a1 += bfhi(ub);
        a0 += bflo(uc); a1 += bfhi(uc);
        a0 += bflo(ud); a1 += bfhi(ud);
        a0 += bflo(ue); a1 += bfhi(ue);
        a0 += bflo(uf); a1 += bfhi(uf);
    }
    for (; p + 8 <= pe; p += 8) {
        int4 c0 = *(const int4*)(col + p);
        int4 c1 = *(const int4*)(col + p + 4);
        unsigned u0 = t32[((size_t)c0.x << 6) + lane];
        unsigned u1 = t32[((size_t)c0.y << 6) + lane];
        unsigned u2 = t32[((size_t)c0.z << 6) + lane];
        unsigned u3 = t32[((size_t)c0.w << 6) + lane];
        unsigned u4 = t32[((size_t)c1.x << 6) + lane];
        unsigned u5 = t32[((size_t)c1.y << 6) + lane];
        unsigned u6 = t32[((size_t)c1.z << 6) + lane];
        unsigned u7 = t32[((size_t)c1.w << 6) + lane];
        a0 += bflo(u0); a1 += bfhi(u0);
        a0 += bflo(u1); a1 += bfhi(u1);
        a0 += bflo(u2); a1 += bfhi(u2);
        a0 += bflo(u3); a1 += bfhi(u3);
        a0 += bflo(u4); a1 += bfhi(u4);
        a0 += bflo(u5); a1 += bfhi(u5);
        a0 += bflo(u6); a1 += bfhi(u6);
        a0 += bflo(u7); a1 += bfhi(u7);
    }
    if (p < pe) {
        int4 c0 = *(const int4*)(col + p);
        unsigned u0 = t32[((size_t)c0.x << 6) + lane];
        unsigned u1 = t32[((size_t)c0.y << 6) + lane];
        unsigned u2 = t32[((size_t)c0.z << 6) + lane];
        unsigned u3 = t32[((size_t)c0.w << 6) + lane];
        a0 += bflo(u0); a1 += bfhi(u0);
        a0 += bflo(u1); a1 += bfhi(u1);
        a0 += bflo(u2); a1 += bfhi(u2);
        a0 += bflo(u3); a1 += bfhi(u3);
    }
    float di = dinv[w];
    BF2 o;
    o.h[0] = (__bf16)fmaxf(di * a0 + bias[lane * 2], 0.f);
    o.h[1] = (__bf16)fmaxf(di * a1 + bias[lane * 2 + 1], 0.f);
    out[(size_t)w * 64 + lane] = o.u;
}

__global__ __launch_bounds__(256) void k_agg64(const unsigned short* __restrict__ t16,
                                               const int* __restrict__ rowptr,
                                               const int* __restrict__ col,
                                               const float* __restrict__ dinv,
                                               const float* __restrict__ bias,
                                               __bf16* __restrict__ out, int n) {
    int w = (int)((blockIdx.x * 256u + threadIdx.x) >> 6);
    int lane = threadIdx.x & 63;
    if (w >= n) return;
    float acc = __uint_as_float((unsigned)t16[(size_t)w * 64 + lane] << 16);
    int p = rowptr[w], pe = rowptr[w + 1];
    for (; p + 16 <= pe; p += 16) {
        int4 c0 = *(const int4*)(col + p);
        int4 c1 = *(const int4*)(col + p + 4);
        int4 c2 = *(const int4*)(col + p + 8);
        int4 c3 = *(const int4*)(col + p + 12);
        unsigned u0 = t16[((size_t)c0.x << 6) + lane];
        unsigned u1 = t16[((size_t)c0.y << 6) + lane];
        unsigned u2 = t16[((size_t)c0.z << 6) + lane];
        unsigned u3 = t16[((size_t)c0.w << 6) + lane];
        unsigned u4 = t16[((size_t)c1.x << 6) + lane];
        unsigned u5 = t16[((size_t)c1.y << 6) + lane];
        unsigned u6 = t16[((size_t)c1.z << 6) + lane];
        unsigned u7 = t16[((size_t)c1.w << 6) + lane];
        unsigned u8 = t16[((size_t)c2.x << 6) + lane];
        unsigned u9 = t16[((size_t)c2.y << 6) + lane];
        unsigned ua = t16[((size_t)c2.z << 6) + lane];
        unsigned ub = t16[((size_t)c2.w << 6) + lane];
        unsigned uc = t16[((size_t)c3.x << 6) + lane];
        unsigned ud = t16[((size_t)c3.y << 6) + lane];
        unsigned ue = t16[((size_t)c3.z << 6) + lane];
        unsigned uf = t16[((size_t)c3.w << 6) + lane];
        acc += __uint_as_float(u0 << 16);
        acc += __uint_as_float(u1 << 16);
        acc += __uint_as_float(u2 << 16);
        acc += __uint_as_float(u3 << 16);
        acc += __uint_as_float(u4 << 16);
        acc += __uint_as_float(u5 << 16);
        acc += __uint_as_float(u6 << 16);
        acc += __uint_as_float(u7 << 16);
        acc += __uint_as_float(u8 << 16);
        acc += __uint_as_float(u9 << 16);
        acc += __uint_as_float(ua << 16);
        acc += __uint_as_float(ub << 16);
        acc += __uint_as_float(uc << 16);
        acc += __uint_as_float(ud << 16);
        acc += __uint_as_float(ue << 16);
        acc += __uint_as_float(uf << 16);
    }
    for (; p + 4 <= pe; p += 4) {
        int4 c0 = *(const int4*)(col + p);
        unsigned u0 = t16[((size_t)c0.x << 6) + lane];
        unsigned u1 = t16[((size_t)c0.y << 6) + lane];
        unsigned u2 = t16[((size_t)c0.z << 6) + lane];
        unsigned u3 = t16[((size_t)c0.w << 6) + lane];
        acc += __uint_as_float(u0 << 16);
        acc += __uint_as_float(u1 << 16);
        acc += __uint_as_float(u2 << 16);
        acc += __uint_as_float(u3 << 16);
    }
    out[(size_t)w * 64 + lane] = (__bf16)fmaxf(dinv[w] * acc + bias[lane], 0.f);
}

// ---------------- fused mean-pool + MLP head ----------------
__global__ __launch_bounds__(256) void k_poolmlp(const unsigned short* __restrict__ h,
                                                 const int* __restrict__ gstart,
                                                 const float* __restrict__ demo,
                                                 const float* __restrict__ Wf1,
                                                 const float* __restrict__ bf1,
                                                 const float* __restrict__ Wf2,
                                                 const float* __restrict__ bf2,
                                                 const float* __restrict__ Wf3,
                                                 const float* __restrict__ bf3,
                                                 float* __restrict__ out, int G) {
    int g = blockIdx.x;
    int tid = threadIdx.x;
    int lane = tid & 63;
    int wv = tid >> 6;
    int s = gstart[g], e = gstart[g + 1];
    float acc = 0.f;
    for (int i = s + wv; i < e; i += 4)
        acc += __uint_as_float((unsigned)h[(size_t)i * 64 + lane] << 16);
    __shared__ float red[4][64];
    __shared__ float zin[72];
    __shared__ float z1[64];
    __shared__ float z2[32];
    red[wv][lane] = acc;
    if (tid >= 64 && tid < 72) zin[tid] = demo[g * 8 + (tid - 64)];
    __syncthreads();
    if (tid < 64) {
        float v = red[0][tid] + red[1][tid] + red[2][tid] + red[3][tid];
        zin[tid] = v / fmaxf((float)(e - s), 1.0f);
    }
    __syncthreads();
    if (tid < 64) {
        float a = bf1[tid];
        for (int k = 0; k < 72; k++) a += zin[k] * Wf1[k * 64 + tid];
        z1[tid] = fmaxf(a, 0.f);
    }
    __syncthreads();
    if (tid < 32) {
        float a2 = bf2[tid];
        for (int k = 0; k < 64; k++) a2 += z1[k] * Wf2[k * 32 + tid];
        z2[tid] = fmaxf(a2, 0.f);
    }
    __syncthreads();
    if (tid < 2) {
        float a3 = bf3[tid];
        for (int k = 0; k < 32; k++) a3 += z2[k] * Wf3[k * 2 + tid];
        out[g * 2 + tid] = a3;
    }
}

extern "C" void kernel_launch(void* const* d_in, const int* in_sizes, int n_in,
                              void* d_out, int out_size, void* d_ws, size_t ws_size,
                              hipStream_t stream) {
    const float* x    = (const float*)d_in[0];
    const int*   ei   = (const int*)d_in[1];
    const int*   batch= (const int*)d_in[2];
    const float* demo = (const float*)d_in[3];
    const float* W1   = (const float*)d_in[4];
    const float* b1   = (const float*)d_in[5];
    const float* W2   = (const float*)d_in[6];
    const float* b2   = (const float*)d_in[7];
    const float* W3   = (const float*)d_in[8];
    const float* b3   = (const float*)d_in[9];
    const float* Wf1  = (const float*)d_in[10];
    const float* bf1  = (const float*)d_in[11];
    const float* Wf2  = (const float*)d_in[12];
    const float* bf2  = (const float*)d_in[13];
    const float* Wf3  = (const float*)d_in[14];
    const float* bf3  = (const float*)d_in[15];
    float* out = (float*)d_out;

    const int n = in_sizes[0] / 128;  // 50000
    const int E = in_sizes[1] / 2;    // 600000
    const int G = in_sizes[3] / 8;    // 100
    const int Epad = E + 3 * n;       // worst-case padded CSR size

    char* ws = (char*)d_ws;
    auto alloc = [&](size_t bytes) {
        char* p = ws;
        ws += (bytes + 255) & ~(size_t)255;
        return p;
    };
    int*    cnt    = (int*)alloc((size_t)n * 4);
    float*  dinv   = (float*)alloc((size_t)n * 4);
    int*    rowptr = (int*)alloc((size_t)(n + 1) * 4);
    int*    fill2  = (int*)alloc((size_t)n * 4);
    int*    col    = (int*)alloc((size_t)Epad * 4);
    __bf16* tbf    = (__bf16*)alloc((size_t)(n + 1) * 128 * 2);  // ts (layers 1/2), row n = 0
    __bf16* hbuf   = (__bf16*)alloc((size_t)n * 128 * 2);        // agg out bf16
    __bf16* t3bf   = (__bf16*)alloc((size_t)(n + 1) * 64 * 2);   // ts layer 3, row n = 0
    __bf16* h3     = (__bf16*)alloc((size_t)n * 64 * 2);         // agg3 out (bf16)
    __bf16* Wp1h   = (__bf16*)alloc(128 * 128 * 2);
    __bf16* Wp1l   = (__bf16*)alloc(128 * 128 * 2);
    __bf16* Wp2h   = (__bf16*)alloc(128 * 128 * 2);
    __bf16* Wp2l   = (__bf16*)alloc(128 * 128 * 2);
    __bf16* Wp3h   = (__bf16*)alloc(128 * 64 * 2);
    __bf16* Wp3l   = (__bf16*)alloc(128 * 64 * 2);
    int*    gstart = (int*)alloc((size_t)(G + 1) * 4);

    const int* srcv = ei;
    const int* dstv = ei + E;

    hipMemsetAsync(cnt, 0, (size_t)n * 4, stream);

    const int EB = (E + 255) / 256;
    // k_pre: EB degree blocks + 1 gstart block + 20 wpack blocks (W1,W2,W3)
    k_pre<<<EB + 21, 256, 0, stream>>>(dstv, cnt, batch, gstart, W1, Wp1h, Wp1l,
                                       W2, W3, Wp2h, Wp2l, Wp3h, Wp3l, E, n, G, EB);
    k_scan<<<1, 1024, 0, stream>>>(cnt, rowptr, fill2, dinv, col,
                                   (unsigned int*)tbf, (unsigned int*)t3bf, n);
    k_csr<<<EB, 256, 0, stream>>>(srcv, dstv, fill2, col, E);

    int waves = (n + 15) / 16;
    int gemm_blocks = (waves + 3) / 4;
    int agg_blocks = (int)(((size_t)n * 64 + 255) / 256);

    // Layer 1: ts = dinv (.) (x@W1); h = relu(dinv*(gather-sum) + b1)
    k_gemm_f32<8><<<gemm_blocks, 256, 0, stream>>>(x, Wp1h, Wp1l, dinv, tbf, n);
    k_agg128<<<agg_blocks, 256, 0, stream>>>((const unsigned int*)tbf, rowptr, col,
                                             dinv, b1, (unsigned int*)hbuf, n);
    // Layer 2
    k_gemm_bf16<8><<<gemm_blocks, 256, 0, stream>>>(hbuf, Wp2h, Wp2l, dinv, tbf, n);
    k_agg128<<<agg_blocks, 256, 0, stream>>>((const unsigned int*)tbf, rowptr, col,
                                             dinv, b2, (unsigned int*)hbuf, n);
    // Layer 3 (128 -> 64)
    k_gemm_bf16<4><<<gemm_blocks, 256, 0, stream>>>(hbuf, Wp3h, Wp3l, dinv, t3bf, n);
    k_agg64<<<agg_blocks, 256, 0, stream>>>((const unsigned short*)t3bf, rowptr, col,
                                            dinv, b3, h3, n);

    k_poolmlp<<<G, 256, 0, stream>>>((const unsigned short*)h3, gstart, demo,
                                     Wf1, bf1, Wf2, bf2, Wf3, bf3, out, G);
}

// Round 12
// 313.143 us; speedup vs baseline: 1.6813x; 1.0967x over previous
//
#include <hip/hip_runtime.h>

// ---------------------------------------------------------------------------
// ROIAwareGCN: 3x GCNConv + mean-pool + MLP.
// R1: atomic pool -> segmented reduction. R2: split-bf16 MFMA GEMM, bf16 t.
// R3: padded CSR. R4: pool+mlp fused; 16-deep agg bursts.
// R5/R6: single-block scan. R7: bucket atomics REGRESSED. R8: LDS sort CRASHED.
// R9: col-only scatter NEUTRAL (scattered writes cost per LINE, not per byte).
// R10: wgt[] eliminated algebraically (dinv folded into GEMM epilogue; agg =
//      pure gather-sum; pad cols -> zero row n).
// R11: k_scan was 44.5us (hidden since R6 below the top-5 cutoff): single
//      block = per-wave serial chunk latency + one CU's store drain. Split
//      into k_sum (13 blocks: partial sums + dinv) and k_out (13 blocks:
//      base = sum of partials, in-block scan, rowptr/fill2/pad-col writes).
//      Store work now spread over 13 CUs; no serial 44us node remains.
// ---------------------------------------------------------------------------

typedef __bf16 bf16x8 __attribute__((ext_vector_type(8)));
typedef float f32x4 __attribute__((ext_vector_type(4)));

__device__ __forceinline__ float bflo(unsigned u) { return __uint_as_float(u << 16); }
__device__ __forceinline__ float bfhi(unsigned u) { return __uint_as_float(u & 0xffff0000u); }

union BF2 {
    __bf16 h[2];
    unsigned u;
};

// ---------------- W pre-pack into MFMA B-fragment layout ----------------
__device__ __forceinline__ void wpack_block(const float* __restrict__ W,
                                            __bf16* __restrict__ hi,
                                            __bf16* __restrict__ lo, int N, int b, int l) {
    int t = b >> 2, c = b & 3;
    int k0 = c * 32 + (l >> 4) * 8;
    int ncol = t * 16 + (l & 15);
    size_t base = ((size_t)b * 64 + l) * 8;
#pragma unroll
    for (int j = 0; j < 8; j++) {
        float v = W[(size_t)(k0 + j) * N + ncol];
        __bf16 h = (__bf16)v;
        hi[base + j] = h;
        lo[base + j] = (__bf16)(v - (float)h);
    }
}

// ---- fused: degree count + graph boundaries + wpack(W1,W2,W3) ----
__global__ void k_pre(const int* __restrict__ dst, int* __restrict__ cnt,
                      const int* __restrict__ batch, int* __restrict__ gstart,
                      const float* __restrict__ W1, __bf16* __restrict__ Wp1h,
                      __bf16* __restrict__ Wp1l,
                      const float* __restrict__ W2, const float* __restrict__ W3,
                      __bf16* __restrict__ Wp2h, __bf16* __restrict__ Wp2l,
                      __bf16* __restrict__ Wp3h, __bf16* __restrict__ Wp3l,
                      int E, int n, int G, int EB) {
    int b = blockIdx.x;
    if (b < EB) {
        int e = b * 256 + threadIdx.x;
        if (e < E) atomicAdd(&cnt[dst[e]], 1);
    } else if (b == EB) {
        int g = threadIdx.x;
        if (g <= G) {
            int lo = 0, hi = n;
            while (lo < hi) {
                int mid = (lo + hi) >> 1;
                if (batch[mid] < g) lo = mid + 1; else hi = mid;
            }
            gstart[g] = lo;  // lower_bound: first i with batch[i] >= g
        }
    } else {
        int b64 = (b - EB - 1) * 4 + (threadIdx.x >> 6);  // 0..79
        int l = threadIdx.x & 63;
        if (b64 < 32) wpack_block(W1, Wp1h, Wp1l, 128, b64, l);
        else if (b64 < 64) wpack_block(W2, Wp2h, Wp2l, 128, b64 - 32, l);
        else if (b64 < 80) wpack_block(W3, Wp3h, Wp3l, 64, b64 - 64, l);
    }
}

// ---------------- scan stage 1: per-chunk padded sums + dinv ----------------
// grid = nchunks (4096 counts per block). Block 0 zeroes row n of ts buffers.
__global__ __launch_bounds__(1024) void k_sum(const int* __restrict__ cnt,
                                              int* __restrict__ partial,
                                              float* __restrict__ dinv,
                                              unsigned int* __restrict__ tz128,
                                              unsigned int* __restrict__ tz64, int n) {
    __shared__ int ws[16];
    int b = blockIdx.x;
    int tid = threadIdx.x;
    int lane = tid & 63;
    int wid = tid >> 6;
    if (b == 0) {  // zero row n of the two gather targets (64 + 32 uints)
        if (tid < 64) tz128[(size_t)n * 64 + tid] = 0u;
        else if (tid < 96) tz64[(size_t)n * 32 + (tid - 64)] = 0u;
    }
    int i0 = (b << 12) + tid * 4;
    int s = 0;
    if (i0 + 3 < n) {
        int4 v = *(const int4*)(cnt + i0);
        float4 dv;
        dv.x = rsqrtf((float)(v.x + 1));
        dv.y = rsqrtf((float)(v.y + 1));
        dv.z = rsqrtf((float)(v.z + 1));
        dv.w = rsqrtf((float)(v.w + 1));
        *(float4*)(dinv + i0) = dv;
        s = ((v.x + 3) & ~3) + ((v.y + 3) & ~3) + ((v.z + 3) & ~3) + ((v.w + 3) & ~3);
    } else if (i0 < n) {
#pragma unroll
        for (int j = 0; j < 4; j++) {
            if (i0 + j < n) {
                int v = cnt[i0 + j];
                dinv[i0 + j] = rsqrtf((float)(v + 1));
                s += (v + 3) & ~3;
            }
        }
    }
#pragma unroll
    for (int d = 32; d > 0; d >>= 1) s += __shfl_xor(s, d);
    if (lane == 0) ws[wid] = s;
    __syncthreads();
    if (tid == 0) {
        int t = 0;
#pragma unroll
        for (int k = 0; k < 16; k++) t += ws[k];
        partial[b] = t;
    }
}

// ---------------- scan stage 2: in-block scan + outputs ----------------
// grid = nchunks. Block base = sum of partial[0..b). Writes rowptr/fill2 (int4),
// pad-col slots (col = n -> zero row), rowptr[n].
__global__ __launch_bounds__(1024) void k_out(const int* __restrict__ cnt,
                                              const int* __restrict__ partial,
                                              int* __restrict__ rowptr,
                                              int* __restrict__ fill2,
                                              int* __restrict__ col,
                                              int n, int nchunks) {
    __shared__ int lsum[16];
    __shared__ int base_s;
    int b = blockIdx.x;
    int tid = threadIdx.x;
    int lane = tid & 63;
    int wid = tid >> 6;
    if (tid == 0) {
        int acc = 0;
        for (int c = 0; c < b; c++) acc += partial[c];
        base_s = acc;
    }
    if (b == 0 && tid == 1) {  // total -> rowptr[n]
        int acc = 0;
        for (int c = 0; c < nchunks; c++) acc += partial[c];
        rowptr[n] = acc;
    }
    int i0 = (b << 12) + tid * 4;
    int v[4], pv[4];
    int s = 0;
    if (i0 < n) {
        if (i0 + 3 < n) {
            int4 vv = *(const int4*)(cnt + i0);
            v[0] = vv.x; v[1] = vv.y; v[2] = vv.z; v[3] = vv.w;
        } else {
#pragma unroll
            for (int j = 0; j < 4; j++) v[j] = (i0 + j < n) ? cnt[i0 + j] : 0;
        }
    } else {
#pragma unroll
        for (int j = 0; j < 4; j++) v[j] = 0;
    }
#pragma unroll
    for (int j = 0; j < 4; j++) {
        pv[j] = (v[j] + 3) & ~3;
        s += pv[j];
    }
    int sc = s;
#pragma unroll
    for (int d = 1; d < 64; d <<= 1) {
        int o = __shfl_up(sc, d);
        if (lane >= d) sc += o;
    }
    int exc = sc - s;
    if (lane == 63) lsum[wid] = sc;
    __syncthreads();
    if (wid == 0) {
        int val = (lane < 16) ? lsum[lane] : 0;
        int sc2 = val;
#pragma unroll
        for (int d = 1; d < 16; d <<= 1) {
            int o = __shfl_up(sc2, d);
            if (lane >= d) sc2 += o;
        }
        if (lane < 16) lsum[lane] = sc2 - val;
    }
    __syncthreads();
    if (i0 >= n) return;
    int off = base_s + lsum[wid] + exc;
    int o0 = off;
    int o1 = o0 + pv[0];
    int o2 = o1 + pv[1];
    int o3 = o2 + pv[2];
    int o4 = o3 + pv[3];
    if (i0 + 3 < n) {
        int4 ov = {o0, o1, o2, o3};
        *(int4*)(rowptr + i0) = ov;
        *(int4*)(fill2 + i0) = ov;
    } else {
        int oo[4] = {o0, o1, o2, o3};
#pragma unroll
        for (int j = 0; j < 4; j++) {
            if (i0 + j < n) {
                rowptr[i0 + j] = oo[j];
                fill2[i0 + j] = oo[j];
            }
        }
    }
    for (int p = o0 + v[0]; p < o1; p++) col[p] = n;
    if (i0 + 1 < n) for (int p = o1 + v[1]; p < o2; p++) col[p] = n;
    if (i0 + 2 < n) for (int p = o2 + v[2]; p < o3; p++) col[p] = n;
    if (i0 + 3 < n) for (int p = o3 + v[3]; p < o4; p++) col[p] = n;
}

// ---------------- CSR scatter: col only ----------------
__global__ void k_csr(const int* __restrict__ src, const int* __restrict__ dst,
                      int* __restrict__ fill2, int* __restrict__ col, int E) {
    int e = blockIdx.x * blockDim.x + threadIdx.x;
    if (e >= E) return;
    int pos = atomicAdd(&fill2[dst[e]], 1);
    col[pos] = src[e];
}

// ---------------- MFMA GEMMs (epilogue scales row by dinv) ----------------
template <int NT>
__global__ __launch_bounds__(256) void k_gemm_f32(const float* __restrict__ A,
                                                  const __bf16* __restrict__ Wp_hi,
                                                  const __bf16* __restrict__ Wp_lo,
                                                  const float* __restrict__ dinv,
                                                  __bf16* __restrict__ Cbf, int n) {
    constexpr int N = NT * 16;
    int wave = (int)((blockIdx.x * 256u + threadIdx.x) >> 6);
    int lane = threadIdx.x & 63;
    int row0 = wave * 16;
    if (row0 >= n) return;
    int m = lane & 15;
    int q = lane >> 4;
    int row = row0 + m;
    if (row >= n) row = n - 1;
    const float* ap = A + (size_t)row * 128 + q * 8;
    bf16x8 ahi[4], alo[4];
#pragma unroll
    for (int c = 0; c < 4; c++) {
        float4 v0 = *(const float4*)(ap + c * 32);
        float4 v1 = *(const float4*)(ap + c * 32 + 4);
        float vv[8] = {v0.x, v0.y, v0.z, v0.w, v1.x, v1.y, v1.z, v1.w};
#pragma unroll
        for (int j = 0; j < 8; j++) {
            __bf16 h = (__bf16)vv[j];
            ahi[c][j] = h;
            alo[c][j] = (__bf16)(vv[j] - (float)h);
        }
    }
    float dscale[4];
#pragma unroll
    for (int r = 0; r < 4; r++) {
        int rr = row0 + q * 4 + r;
        dscale[r] = dinv[rr < n ? rr : (n - 1)];
    }
#pragma unroll
    for (int t = 0; t < NT; t++) {
        f32x4 acc = {0.f, 0.f, 0.f, 0.f};
#pragma unroll
        for (int c = 0; c < 4; c++) {
            size_t off = ((size_t)(t * 4 + c) * 64 + lane) * 8;
            bf16x8 bh = *(const bf16x8*)(Wp_hi + off);
            bf16x8 bl = *(const bf16x8*)(Wp_lo + off);
            acc = __builtin_amdgcn_mfma_f32_16x16x32_bf16(ahi[c], bh, acc, 0, 0, 0);
            acc = __builtin_amdgcn_mfma_f32_16x16x32_bf16(alo[c], bh, acc, 0, 0, 0);
            acc = __builtin_amdgcn_mfma_f32_16x16x32_bf16(ahi[c], bl, acc, 0, 0, 0);
        }
        int colx = t * 16 + m;
#pragma unroll
        for (int r = 0; r < 4; r++) {
            int orow = row0 + q * 4 + r;
            if (orow < n) Cbf[(size_t)orow * N + colx] = (__bf16)(acc[r] * dscale[r]);
        }
    }
}

template <int NT>
__global__ __launch_bounds__(256) void k_gemm_bf16(const __bf16* __restrict__ A,
                                                   const __bf16* __restrict__ Wp_hi,
                                                   const __bf16* __restrict__ Wp_lo,
                                                   const float* __restrict__ dinv,
                                                   __bf16* __restrict__ Cbf, int n) {
    constexpr int N = NT * 16;
    int wave = (int)((blockIdx.x * 256u + threadIdx.x) >> 6);
    int lane = threadIdx.x & 63;
    int row0 = wave * 16;
    if (row0 >= n) return;
    int m = lane & 15;
    int q = lane >> 4;
    int row = row0 + m;
    if (row >= n) row = n - 1;
    const __bf16* ap = A + (size_t)row * 128 + q * 8;
    bf16x8 a[4];
#pragma unroll
    for (int c = 0; c < 4; c++) a[c] = *(const bf16x8*)(ap + c * 32);
    float dscale[4];
#pragma unroll
    for (int r = 0; r < 4; r++) {
        int rr = row0 + q * 4 + r;
        dscale[r] = dinv[rr < n ? rr : (n - 1)];
    }
#pragma unroll
    for (int t = 0; t < NT; t++) {
        f32x4 acc = {0.f, 0.f, 0.f, 0.f};
#pragma unroll
        for (int c = 0; c < 4; c++) {
            size_t off = ((size_t)(t * 4 + c) * 64 + lane) * 8;
            bf16x8 bh = *(const bf16x8*)(Wp_hi + off);
            bf16x8 bl = *(const bf16x8*)(Wp_lo + off);
            acc = __builtin_amdgcn_mfma_f32_16x16x32_bf16(a[c], bh, acc, 0, 0, 0);
            acc = __builtin_amdgcn_mfma_f32_16x16x32_bf16(a[c], bl, acc, 0, 0, 0);
        }
        int colx = t * 16 + m;
#pragma unroll
        for (int r = 0; r < 4; r++) {
            int orow = row0 + q * 4 + r;
            if (orow < n) Cbf[(size_t)orow * N + colx] = (__bf16)(acc[r] * dscale[r]);
        }
    }
}

// ---------------- aggregation: pure gather-sum over pre-scaled ts ----------------
__global__ __launch_bounds__(256) void k_agg128(const unsigned int* __restrict__ t32,
                                                const int* __restrict__ rowptr,
                                                const int* __restrict__ col,
                                                const float* __restrict__ dinv,
                                                const float* __restrict__ bias,
                                                unsigned int* __restrict__ out, int n) {
    int w = (int)((blockIdx.x * 256u + threadIdx.x) >> 6);
    int lane = threadIdx.x & 63;
    if (w >= n) return;
    unsigned us = t32[(size_t)w * 64 + lane];
    float a0 = bflo(us);
    float a1 = bfhi(us);
    int p = rowptr[w], pe = rowptr[w + 1];
    for (; p + 16 <= pe; p += 16) {  // 16 gathers in flight
        int4 c0 = *(const int4*)(col + p);
        int4 c1 = *(const int4*)(col + p + 4);
        int4 c2 = *(const int4*)(col + p + 8);
        int4 c3 = *(const int4*)(col + p + 12);
        unsigned u0 = t32[((size_t)c0.x << 6) + lane];
        unsigned u1 = t32[((size_t)c0.y << 6) + lane];
        unsigned u2 = t32[((size_t)c0.z << 6) + lane];
        unsigned u3 = t32[((size_t)c0.w << 6) + lane];
        unsigned u4 = t32[((size_t)c1.x << 6) + lane];
        unsigned u5 = t32[((size_t)c1.y << 6) + lane];
        unsigned u6 = t32[((size_t)c1.z << 6) + lane];
        unsigned u7 = t32[((size_t)c1.w << 6) + lane];
        unsigned u8 = t32[((size_t)c2.x << 6) + lane];
        unsigned u9 = t32[((size_t)c2.y << 6) + lane];
        unsigned ua = t32[((size_t)c2.z << 6) + lane];
        unsigned ub = t32[((size_t)c2.w << 6) + lane];
        unsigned uc = t32[((size_t)c3.x << 6) + lane];
        unsigned ud = t32[((size_t)c3.y << 6) + lane];
        unsigned ue = t32[((size_t)c3.z << 6) + lane];
        unsigned uf = t32[((size_t)c3.w << 6) + lane];
        a0 += bflo(u0); a1 += bfhi(u0);
        a0 += bflo(u1); a1 += bfhi(u1);
        a0 += bflo(u2); a1 += bfhi(u2);
        a0 += bflo(u3); a1 += bfhi(u3);
        a0 += bflo(u4); a1 += bfhi(u4);
        a0 += bflo(u5); a1 += bfhi(u5);
        a0 += bflo(u6); a1 += bfhi(u6);
        a0 += bflo(u7); a1 += bfhi(u7);
        a0 += bflo(u8); a1 += bfhi(u8);
        a0 += bflo(u9); a1 += bfhi(u9);
        a0 += bflo(ua); a1 += bfhi(ua);
        a0 += bflo(ub); a1 += bfhi(ub);
        a0 += bflo(uc); a1 += bfhi(uc);
        a0 += bflo(ud); a1 += bfhi(ud);
        a0 += bflo(ue); a1 += bfhi(ue);
        a0 += bflo(uf); a1 += bfhi(uf);
    }
    for (; p + 8 <= pe; p += 8) {
        int4 c0 = *(const int4*)(col + p);
        int4 c1 = *(const int4*)(col + p + 4);
        unsigned u0 = t32[((size_t)c0.x << 6) + lane];
        unsigned u1 = t32[((size_t)c0.y << 6) + lane];
        unsigned u2 = t32[((size_t)c0.z << 6) + lane];
        unsigned u3 = t32[((size_t)c0.w << 6) + lane];
        unsigned u4 = t32[((size_t)c1.x << 6) + lane];
        unsigned u5 = t32[((size_t)c1.y << 6) + lane];
        unsigned u6 = t32[((size_t)c1.z << 6) + lane];
        unsigned u7 = t32[((size_t)c1.w << 6) + lane];
        a0 += bflo(u0); a1 += bfhi(u0);
        a0 += bflo(u1); a1 += bfhi(u1);
        a0 += bflo(u2); a1 += bfhi(u2);
        a0 += bflo(u3); a1 += bfhi(u3);
        a0 += bflo(u4); a1 += bfhi(u4);
        a0 += bflo(u5); a1 += bfhi(u5);
        a0 += bflo(u6); a1 += bfhi(u6);
        a0 += bflo(u7); a1 += bfhi(u7);
    }
    if (p < pe) {
        int4 c0 = *(const int4*)(col + p);
        unsigned u0 = t32[((size_t)c0.x << 6) + lane];
        unsigned u1 = t32[((size_t)c0.y << 6) + lane];
        unsigned u2 = t32[((size_t)c0.z << 6) + lane];
        unsigned u3 = t32[((size_t)c0.w << 6) + lane];
        a0 += bflo(u0); a1 += bfhi(u0);
        a0 += bflo(u1); a1 += bfhi(u1);
        a0 += bflo(u2); a1 += bfhi(u2);
        a0 += bflo(u3); a1 += bfhi(u3);
    }
    float di = dinv[w];
    BF2 o;
    o.h[0] = (__bf16)fmaxf(di * a0 + bias[lane * 2], 0.f);
    o.h[1] = (__bf16)fmaxf(di * a1 + bias[lane * 2 + 1], 0.f);
    out[(size_t)w * 64 + lane] = o.u;
}

__global__ __launch_bounds__(256) void k_agg64(const unsigned short* __restrict__ t16,
                                               const int* __restrict__ rowptr,
                                               const int* __restrict__ col,
                                               const float* __restrict__ dinv,
                                               const float* __restrict__ bias,
                                               __bf16* __restrict__ out, int n) {
    int w = (int)((blockIdx.x * 256u + threadIdx.x) >> 6);
    int lane = threadIdx.x & 63;
    if (w >= n) return;
    float acc = __uint_as_float((unsigned)t16[(size_t)w * 64 + lane] << 16);
    int p = rowptr[w], pe = rowptr[w + 1];
    for (; p + 16 <= pe; p += 16) {
        int4 c0 = *(const int4*)(col + p);
        int4 c1 = *(const int4*)(col + p + 4);
        int4 c2 = *(const int4*)(col + p + 8);
        int4 c3 = *(const int4*)(col + p + 12);
        unsigned u0 = t16[((size_t)c0.x << 6) + lane];
        unsigned u1 = t16[((size_t)c0.y << 6) + lane];
        unsigned u2 = t16[((size_t)c0.z << 6) + lane];
        unsigned u3 = t16[((size_t)c0.w << 6) + lane];
        unsigned u4 = t16[((size_t)c1.x << 6) + lane];
        unsigned u5 = t16[((size_t)c1.y << 6) + lane];
        unsigned u6 = t16[((size_t)c1.z << 6) + lane];
        unsigned u7 = t16[((size_t)c1.w << 6) + lane];
        unsigned u8 = t16[((size_t)c2.x << 6) + lane];
        unsigned u9 = t16[((size_t)c2.y << 6) + lane];
        unsigned ua = t16[((size_t)c2.z << 6) + lane];
        unsigned ub = t16[((size_t)c2.w << 6) + lane];
        unsigned uc = t16[((size_t)c3.x << 6) + lane];
        unsigned ud = t16[((size_t)c3.y << 6) + lane];
        unsigned ue = t16[((size_t)c3.z << 6) + lane];
        unsigned uf = t16[((size_t)c3.w << 6) + lane];
        acc += __uint_as_float(u0 << 16);
        acc += __uint_as_float(u1 << 16);
        acc += __uint_as_float(u2 << 16);
        acc += __uint_as_float(u3 << 16);
        acc += __uint_as_float(u4 << 16);
        acc += __uint_as_float(u5 << 16);
        acc += __uint_as_float(u6 << 16);
        acc += __uint_as_float(u7 << 16);
        acc += __uint_as_float(u8 << 16);
        acc += __uint_as_float(u9 << 16);
        acc += __uint_as_float(ua << 16);
        acc += __uint_as_float(ub << 16);
        acc += __uint_as_float(uc << 16);
        acc += __uint_as_float(ud << 16);
        acc += __uint_as_float(ue << 16);
        acc += __uint_as_float(uf << 16);
    }
    for (; p + 4 <= pe; p += 4) {
        int4 c0 = *(const int4*)(col + p);
        unsigned u0 = t16[((size_t)c0.x << 6) + lane];
        unsigned u1 = t16[((size_t)c0.y << 6) + lane];
        unsigned u2 = t16[((size_t)c0.z << 6) + lane];
        unsigned u3 = t16[((size_t)c0.w << 6) + lane];
        acc += __uint_as_float(u0 << 16);
        acc += __uint_as_float(u1 << 16);
        acc += __uint_as_float(u2 << 16);
        acc += __uint_as_float(u3 << 16);
    }
    out[(size_t)w * 64 + lane] = (__bf16)fmaxf(dinv[w] * acc + bias[lane], 0.f);
}

// ---------------- fused mean-pool + MLP head ----------------
__global__ __launch_bounds__(256) void k_poolmlp(const unsigned short* __restrict__ h,
                                                 const int* __restrict__ gstart,
                                                 const float* __restrict__ demo,
                                                 const float* __restrict__ Wf1,
                                                 const float* __restrict__ bf1,
                                                 const float* __restrict__ Wf2,
                                                 const float* __restrict__ bf2,
                                                 const float* __restrict__ Wf3,
                                                 const float* __restrict__ bf3,
                                                 float* __restrict__ out, int G) {
    int g = blockIdx.x;
    int tid = threadIdx.x;
    int lane = tid & 63;
    int wv = tid >> 6;
    int s = gstart[g], e = gstart[g + 1];
    float acc = 0.f;
    for (int i = s + wv; i < e; i += 4)
        acc += __uint_as_float((unsigned)h[(size_t)i * 64 + lane] << 16);
    __shared__ float red[4][64];
    __shared__ float zin[72];
    __shared__ float z1[64];
    __shared__ float z2[32];
    red[wv][lane] = acc;
    if (tid >= 64 && tid < 72) zin[tid] = demo[g * 8 + (tid - 64)];
    __syncthreads();
    if (tid < 64) {
        float v = red[0][tid] + red[1][tid] + red[2][tid] + red[3][tid];
        zin[tid] = v / fmaxf((float)(e - s), 1.0f);
    }
    __syncthreads();
    if (tid < 64) {
        float a = bf1[tid];
        for (int k = 0; k < 72; k++) a += zin[k] * Wf1[k * 64 + tid];
        z1[tid] = fmaxf(a, 0.f);
    }
    __syncthreads();
    if (tid < 32) {
        float a2 = bf2[tid];
        for (int k = 0; k < 64; k++) a2 += z1[k] * Wf2[k * 32 + tid];
        z2[tid] = fmaxf(a2, 0.f);
    }
    __syncthreads();
    if (tid < 2) {
        float a3 = bf3[tid];
        for (int k = 0; k < 32; k++) a3 += z2[k] * Wf3[k * 2 + tid];
        out[g * 2 + tid] = a3;
    }
}

extern "C" void kernel_launch(void* const* d_in, const int* in_sizes, int n_in,
                              void* d_out, int out_size, void* d_ws, size_t ws_size,
                              hipStream_t stream) {
    const float* x    = (const float*)d_in[0];
    const int*   ei   = (const int*)d_in[1];
    const int*   batch= (const int*)d_in[2];
    const float* demo = (const float*)d_in[3];
    const float* W1   = (const float*)d_in[4];
    const float* b1   = (const float*)d_in[5];
    const float* W2   = (const float*)d_in[6];
    const float* b2   = (const float*)d_in[7];
    const float* W3   = (const float*)d_in[8];
    const float* b3   = (const float*)d_in[9];
    const float* Wf1  = (const float*)d_in[10];
    const float* bf1  = (const float*)d_in[11];
    const float* Wf2  = (const float*)d_in[12];
    const float* bf2  = (const float*)d_in[13];
    const float* Wf3  = (const float*)d_in[14];
    const float* bf3  = (const float*)d_in[15];
    float* out = (float*)d_out;

    const int n = in_sizes[0] / 128;  // 50000
    const int E = in_sizes[1] / 2;    // 600000
    const int G = in_sizes[3] / 8;    // 100
    const int Epad = E + 3 * n;       // worst-case padded CSR size
    const int nchunks = (n + 4095) / 4096;

    char* ws = (char*)d_ws;
    auto alloc = [&](size_t bytes) {
        char* p = ws;
        ws += (bytes + 255) & ~(size_t)255;
        return p;
    };
    int*    cnt    = (int*)alloc((size_t)n * 4);
    float*  dinv   = (float*)alloc((size_t)n * 4);
    int*    rowptr = (int*)alloc((size_t)(n + 1) * 4);
    int*    fill2  = (int*)alloc((size_t)n * 4);
    int*    partial= (int*)alloc((size_t)nchunks * 4);
    int*    col    = (int*)alloc((size_t)Epad * 4);
    __bf16* tbf    = (__bf16*)alloc((size_t)(n + 1) * 128 * 2);  // ts (layers 1/2), row n = 0
    __bf16* hbuf   = (__bf16*)alloc((size_t)n * 128 * 2);        // agg out bf16
    __bf16* t3bf   = (__bf16*)alloc((size_t)(n + 1) * 64 * 2);   // ts layer 3, row n = 0
    __bf16* h3     = (__bf16*)alloc((size_t)n * 64 * 2);         // agg3 out (bf16)
    __bf16* Wp1h   = (__bf16*)alloc(128 * 128 * 2);
    __bf16* Wp1l   = (__bf16*)alloc(128 * 128 * 2);
    __bf16* Wp2h   = (__bf16*)alloc(128 * 128 * 2);
    __bf16* Wp2l   = (__bf16*)alloc(128 * 128 * 2);
    __bf16* Wp3h   = (__bf16*)alloc(128 * 64 * 2);
    __bf16* Wp3l   = (__bf16*)alloc(128 * 64 * 2);
    int*    gstart = (int*)alloc((size_t)(G + 1) * 4);

    const int* srcv = ei;
    const int* dstv = ei + E;

    hipMemsetAsync(cnt, 0, (size_t)n * 4, stream);

    const int EB = (E + 255) / 256;
    // k_pre: EB degree blocks + 1 gstart block + 20 wpack blocks (W1,W2,W3)
    k_pre<<<EB + 21, 256, 0, stream>>>(dstv, cnt, batch, gstart, W1, Wp1h, Wp1l,
                                       W2, W3, Wp2h, Wp2l, Wp3h, Wp3l, E, n, G, EB);
    // parallel scan: partial sums -> per-chunk scan + writes
    k_sum<<<nchunks, 1024, 0, stream>>>(cnt, partial, dinv,
                                        (unsigned int*)tbf, (unsigned int*)t3bf, n);
    k_out<<<nchunks, 1024, 0, stream>>>(cnt, partial, rowptr, fill2, col, n, nchunks);
    k_csr<<<EB, 256, 0, stream>>>(srcv, dstv, fill2, col, E);

    int waves = (n + 15) / 16;
    int gemm_blocks = (waves + 3) / 4;
    int agg_blocks = (int)(((size_t)n * 64 + 255) / 256);

    // Layer 1: ts = dinv (.) (x@W1); h = relu(dinv*(gather-sum) + b1)
    k_gemm_f32<8><<<gemm_blocks, 256, 0, stream>>>(x, Wp1h, Wp1l, dinv, tbf, n);
    k_agg128<<<agg_blocks, 256, 0, stream>>>((const unsigned int*)tbf, rowptr, col,
                                             dinv, b1, (unsigned int*)hbuf, n);
    // Layer 2
    k_gemm_bf16<8><<<gemm_blocks, 256, 0, stream>>>(hbuf, Wp2h, Wp2l, dinv, tbf, n);
    k_agg128<<<agg_blocks, 256, 0, stream>>>((const unsigned int*)tbf, rowptr, col,
                                             dinv, b2, (unsigned int*)hbuf, n);
    // Layer 3 (128 -> 64)
    k_gemm_bf16<4><<<gemm_blocks, 256, 0, stream>>>(hbuf, Wp3h, Wp3l, dinv, t3bf, n);
    k_agg64<<<agg_blocks, 256, 0, stream>>>((const unsigned short*)t3bf, rowptr, col,
                                            dinv, b3, h3, n);

    k_poolmlp<<<G, 256, 0, stream>>>((const unsigned short*)h3, gstart, demo,
                                     Wf1, bf1, Wf2, bf2, Wf3, bf3, out, G);
}